// Round 10
// baseline (815.860 us; speedup 1.0000x reference)
//
#include <hip/hip_runtime.h>
#include <cfloat>

#define N_PTS 4096
#define NB    4
#define KNN   20
#define EPSB  1e-5f
#define NSL   4          // knn candidate slices per batch-row (R22: NSL=8 regressed net)

typedef short s8v __attribute__((ext_vector_type(8)));
typedef float f4v __attribute__((ext_vector_type(4)));

// ---------------------------------------------------------------------------
// bf16 hi/lo split (round-to-nearest-even both halves)
// ---------------------------------------------------------------------------
__device__ __forceinline__ void bf16split(float x, unsigned short* h, unsigned short* l)
{
    unsigned u = __builtin_bit_cast(unsigned, x);
    unsigned hb = (u + 0x7fffu + ((u >> 16) & 1u)) >> 16;
    float hf = __builtin_bit_cast(float, hb << 16);
    float res = x - hf;
    unsigned u2 = __builtin_bit_cast(unsigned, res);
    unsigned lb = (u2 + 0x7fffu + ((u2 >> 16) & 1u)) >> 16;
    *h = (unsigned short)hb;
    *l = (unsigned short)lb;
}

// ---------------------------------------------------------------------------
// Packed key: fp32 distance (top 24 bits) | 8-bit lane-local ordinal.
// ---------------------------------------------------------------------------
__device__ __forceinline__ unsigned packkey(float d, int lc)
{
    d = fmaxf(d, 0.f);
    unsigned u = __builtin_bit_cast(unsigned, d);
    return (u & 0xFFFFFF00u) | (unsigned)lc;
}

// compare-exchange: a=min, b=max  (v_min_u32 + v_max_u32)
__device__ __forceinline__ void ce(unsigned& a, unsigned& b)
{
    unsigned lo = a < b ? a : b;
    b = a < b ? b : a;
    a = lo;
}

// ---------------------------------------------------------------------------
// R23 batch-4 top-20 maintenance (verified passing R23/R24): sort-4 (5 CE) +
// half-clean (4 min, exact 20-of-24) + bitonic-4 tail (4 CE) + Batcher
// odd-even merge(16,4) (33 CE).
// ---------------------------------------------------------------------------
__device__ __forceinline__ void insert4k(unsigned b0, unsigned b1, unsigned b2, unsigned b3,
                                         unsigned (&k)[KNN])
{
    ce(b0, b1); ce(b2, b3); ce(b0, b2); ce(b1, b3); ce(b1, b2);
    k[16] = k[16] < b3 ? k[16] : b3;
    k[17] = k[17] < b2 ? k[17] : b2;
    k[18] = k[18] < b1 ? k[18] : b1;
    k[19] = k[19] < b0 ? k[19] : b0;
    ce(k[16], k[18]); ce(k[17], k[19]); ce(k[16], k[17]); ce(k[18], k[19]);
    // Batcher odd-even merge(16,4)
    ce(k[0],  k[16]); ce(k[8],  k[16]); ce(k[4],  k[8]);  ce(k[12], k[16]);
    ce(k[2],  k[18]); ce(k[10], k[18]); ce(k[6],  k[10]); ce(k[14], k[18]);
    ce(k[2],  k[4]);  ce(k[6],  k[8]);  ce(k[10], k[12]); ce(k[14], k[16]);
    ce(k[1],  k[17]); ce(k[9],  k[17]); ce(k[5],  k[9]);  ce(k[13], k[17]);
    ce(k[3],  k[19]); ce(k[11], k[19]); ce(k[7],  k[11]); ce(k[15], k[19]);
    ce(k[3],  k[5]);  ce(k[7],  k[9]);  ce(k[11], k[13]); ce(k[15], k[17]);
    ce(k[1],  k[2]);  ce(k[3],  k[4]);  ce(k[5],  k[6]);  ce(k[7],  k[8]);
    ce(k[9],  k[10]); ce(k[11], k[12]); ce(k[13], k[14]); ce(k[15], k[16]);
    ce(k[17], k[18]);
}

// async global->LDS, 16B per lane; LDS dest = wave-uniform base + lane*16
__device__ __forceinline__ void gl2lds16(const void* g, void* l)
{
    __builtin_amdgcn_global_load_lds(
        (const __attribute__((address_space(1))) unsigned int*)g,
        (__attribute__((address_space(3))) unsigned int*)l,
        16, 0, 0);
}

// 16B-chunk swizzle (involution): chunk g lives at LDS chunk g ^ f(g).
__device__ __forceinline__ int swz(int g)
{
    return g ^ (((g >> 3) ^ (g >> 6)) & 7);
}

// monotone fp32 <-> u32 order-preserving encode (for atomicMax reduction)
__device__ __forceinline__ unsigned encf(float f)
{
    unsigned u = __builtin_bit_cast(unsigned, f);
    return (u & 0x80000000u) ? ~u : (u | 0x80000000u);
}
__device__ __forceinline__ float decf(unsigned u)
{
    return (u & 0x80000000u) ? __builtin_bit_cast(float, u ^ 0x80000000u)
                             : __builtin_bit_cast(float, ~u);
}

// ---------------------------------------------------------------------------
// R30: fused stage-0 prep (verified win).
// ---------------------------------------------------------------------------
__global__ __launch_bounds__(256)
void prep0(const float* __restrict__ x, float* __restrict__ xx,
           unsigned short* __restrict__ Ghi, unsigned short* __restrict__ Glo)
{
    int b = blockIdx.y;
    int i = blockIdx.x * 256 + threadIdx.x;
    const float* r = x + ((long)b * N_PTS + i) * 3;
    float v0 = r[0], v1 = r[1], v2 = r[2];
    float s = 0.f;
    s = fmaf(v0, v0, s);
    s = fmaf(v1, v1, s);
    s = fmaf(v2, v2, s);
    xx[(long)b * N_PTS + i] = s;

    float cv[3] = {v0, v1, v2};
    long o = ((long)b * N_PTS + i) * 32;
#pragma unroll
    for (int q = 0; q < 4; q++) {
        s8v hv, lv;
#pragma unroll
        for (int e = 0; e < 8; e++) {
            int k = q * 8 + e;
            float xv = (k < 3) ? cv[k] : 0.f;
            unsigned short h, l;
            bf16split(xv, &h, &l);
            hv[e] = (short)h;
            lv[e] = (short)l;
        }
        *(s8v*)&Ghi[o + q * 8] = hv;
        *(s8v*)&Glo[o + q * 8] = lv;
    }
}

// ---------------------------------------------------------------------------
// R32: barrier-free wave-private knn.
//   Elimination R25-R29: wall = block-wide barrier convoy (VALU floor ~18us
//   vs 101us wall; no pipe >30% per-SIMD). Fix: each wave stages its OWN
//   16-row dbuf tile (cb[wave][2][hi/lo]) -> no cross-wave hazards -> ZERO
//   barriers in the main loop. Per-wave ordering: fragment ds_reads ->
//   lgkmcnt(0)+sched_barrier -> STAGE(tile+2) mid-iter -> compute; top of
//   next iter s_waitcnt vmcnt(0) (per-wave, spill-robust). Stage drain
//   distance = 1 compute phase >= L2-hit latency (slices L2-resident via
//   R29 XCD mapping). 2 query-tiles per wave (R28 verified structure)
//   halve per-wave L2 re-reads; grid 512 = 2 blocks/CU. xx staged to LDS
//   (removes in-loop global loads). mk epilogue wave-private behind one
//   end barrier. Keys lc=it*4+r (16-row tiles) = verified R23 encoding.
// ---------------------------------------------------------------------------
template<int KDP>
__global__ __launch_bounds__(256, 2)
void fused_knn_mfma13(const unsigned short* __restrict__ Ghi,
                      const unsigned short* __restrict__ Glo,
                      const float* __restrict__ xx,
                      float* __restrict__ knnd, int* __restrict__ knni)
{
    constexpr int KS = KDP / 32;
    constexpr int PL = 16 * KDP;       // shorts per plane per buffer
    __shared__ union ShU {
        short cb[4][2][2][PL];         // [wave][buf][hi/lo][16 rows] (private)
        unsigned mk[8][16][4][21];     // epilogue only (one barrier fences)
    } sh;
    __shared__ float xxs[1024];

    int tid = threadIdx.x;
    int w = tid >> 6, L = tid & 63;
    int n = L & 15;
    int quad = L >> 4;

    // XCD decode for 512 blocks: group g = b*NSL+slice (16 groups x 32
    // query-tile-pairs); all blocks of group g have bid%8 == g%8.
    int bid = blockIdx.x;
    int xcd = bid & 7;
    int slot = bid >> 3;               // 0..63
    int g = xcd + (slot >> 5) * 8;     // 0..15
    int qt2 = slot & 31;
    int slice = g & 3;
    int b = g >> 2;
    int q0 = qt2 * 128, qw = w * 16;

    const unsigned short* Gh = Ghi + (long)b * N_PTS * KDP;
    const unsigned short* Gl = Glo + (long)b * N_PTS * KDP;
    const float* xxb = xx + (long)b * N_PTS;

    s8v qhi0[KS], qlo0[KS], qhi1[KS], qlo1[KS];
    long qbase = (long)(q0 + qw + n) * KDP + quad * 8;
#pragma unroll
    for (int ks = 0; ks < KS; ks++) {
        qhi0[ks] = *(const s8v*)&Gh[qbase + ks * 32];
        qlo0[ks] = *(const s8v*)&Gl[qbase + ks * 32];
        qhi1[ks] = *(const s8v*)&Gh[qbase + (long)64 * KDP + ks * 32];
        qlo1[ks] = *(const s8v*)&Gl[qbase + (long)64 * KDP + ks * 32];
    }
    float xq0 = xxb[q0 + qw + n];
    float xq1 = xxb[q0 + 64 + qw + n];

    unsigned k20a[KNN], k20b[KNN];
#pragma unroll
    for (int j = 0; j < KNN; j++) { k20a[j] = 0xFFFFFFFFu; k20b[j] = 0xFFFFFFFFu; }

    int po[KS];
#pragma unroll
    for (int ks = 0; ks < KS; ks++)
        po[ks] = swz(n * (KDP / 8) + quad + ks * 4) * 8;

    // per-wave stage: 16-row tile -> own buffer; KS calls/plane, 1KB each.
    auto STAGE = [&](int buf, int tile) {
        long tb = (long)(slice * 1024 + tile * 16) * KDP;
        const char* srch = (const char*)(Gh + tb);
        const char* srcl = (const char*)(Gl + tb);
        char* dsth = (char*)&sh.cb[w][buf][0][0];
        char* dstl = (char*)&sh.cb[w][buf][1][0];
#pragma unroll
        for (int c = 0; c < KS; c++) {
            int gs = swz(c * 64 + L);
            gl2lds16(srch + gs * 16, dsth + c * 1024);
            gl2lds16(srcl + gs * 16, dstl + c * 1024);
        }
    };

    // cooperative xx stage (read-only after the single init barrier)
    *(float4*)&xxs[tid * 4] = *(const float4*)&xxb[slice * 1024 + tid * 4];

    STAGE(0, 0);
    STAGE(1, 1);
    __syncthreads();   // xxs visible (also drains prologue stages)

    for (int it = 0; it < 64; it++) {
        asm volatile("s_waitcnt vmcnt(0)" ::: "memory");   // own stages done
        __builtin_amdgcn_sched_barrier(0);
        int cur = it & 1;
        const short* Ch = &sh.cb[w][cur][0][0];
        const short* Cl = &sh.cb[w][cur][1][0];
        s8v chi[KS], clo[KS];
#pragma unroll
        for (int ks = 0; ks < KS; ks++) {
            chi[ks] = *(const s8v*)&Ch[po[ks]];
            clo[ks] = *(const s8v*)&Cl[po[ks]];
        }
        float4 xc4 = *(const float4*)&xxs[it * 16 + quad * 4];
        asm volatile("s_waitcnt lgkmcnt(0)" ::: "memory");  // frags in regs
        __builtin_amdgcn_sched_barrier(0);
        if (it < 62) STAGE(cur, it + 2);   // overwrite safe; drains next iter+1

        f4v a0 = {0.f, 0.f, 0.f, 0.f};
        f4v a1 = {0.f, 0.f, 0.f, 0.f};
#pragma unroll
        for (int ks = 0; ks < KS; ks++) {
            a0 = __builtin_amdgcn_mfma_f32_16x16x32_bf16(chi[ks], qhi0[ks], a0, 0, 0, 0);
            a0 = __builtin_amdgcn_mfma_f32_16x16x32_bf16(chi[ks], qlo0[ks], a0, 0, 0, 0);
            a0 = __builtin_amdgcn_mfma_f32_16x16x32_bf16(clo[ks], qhi0[ks], a0, 0, 0, 0);
            a1 = __builtin_amdgcn_mfma_f32_16x16x32_bf16(chi[ks], qhi1[ks], a1, 0, 0, 0);
            a1 = __builtin_amdgcn_mfma_f32_16x16x32_bf16(chi[ks], qlo1[ks], a1, 0, 0, 0);
            a1 = __builtin_amdgcn_mfma_f32_16x16x32_bf16(clo[ks], qhi1[ks], a1, 0, 0, 0);
        }
        float xcv[4] = {xc4.x, xc4.y, xc4.z, xc4.w};
        unsigned c0[4], c1[4];
#pragma unroll
        for (int r = 0; r < 4; r++) {
            c0[r] = packkey(xq0 + xcv[r] - 2.f * a0[r], it * 4 + r);
            c1[r] = packkey(xq1 + xcv[r] - 2.f * a1[r], it * 4 + r);
        }
        insert4k(c0[0], c0[1], c0[2], c0[3], k20a);
        insert4k(c1[0], c1[1], c1[2], c1[3], k20b);
    }

    __syncthreads();   // all waves done with cb before mk-union writes
#pragma unroll
    for (int j = 0; j < KNN; j++) {
        sh.mk[w][n][quad][j]     = k20a[j];
        sh.mk[4 + w][n][quad][j] = k20b[j];
    }
    // wave-private: wave w reads only mk[w], mk[4+w] which it wrote (in-order)
    if (L < 16) {
#pragma unroll
        for (int qs = 0; qs < 2; qs++) {
            int ww = qs * 4 + w;
            int p[4] = {0, 0, 0, 0};
            long o = (((long)b * NSL + slice) * N_PTS + (q0 + qs * 64 + qw + L)) * KNN;
#pragma unroll
            for (int j = 0; j < KNN; j++) {
                unsigned bd = 0xFFFFFF00u; int bi = 0x7fffffff; int bq = 0;
#pragma unroll
                for (int qd = 0; qd < 4; qd++) {
                    unsigned kk = sh.mk[ww][L][qd][p[qd]];
                    unsigned db = kk & 0xFFFFFF00u;
                    int lc = (int)(kk & 0xFFu);
                    int ci = slice * 1024 + (lc >> 2) * 16 + qd * 4 + (lc & 3);
                    if (db < bd || (db == bd && ci < bi)) { bd = db; bi = ci; bq = qd; }
                }
                knnd[o + j] = __builtin_bit_cast(float, bd);
                knni[o + j] = bi;
                p[bq]++;
            }
        }
    }
}

// ---------------------------------------------------------------------------
__global__ void knn_merge4(const float* __restrict__ knnd, const int* __restrict__ knni,
                           int* __restrict__ idxOut)
{
    int id = blockIdx.x * 256 + threadIdx.x;
    int b = id / N_PTS, i = id % N_PTS;
    const float* dl[NSL]; const int* il[NSL];
#pragma unroll
    for (int qt = 0; qt < NSL; qt++) {
        dl[qt] = knnd + (((long)b * NSL + qt) * N_PTS + i) * KNN;
        il[qt] = knni + (((long)b * NSL + qt) * N_PTS + i) * KNN;
    }
    int p[NSL];
#pragma unroll
    for (int qt = 0; qt < NSL; qt++) p[qt] = 0;
    int* o = idxOut + (long)id * KNN;
#pragma unroll
    for (int j = 0; j < KNN; j++) {
        float best = FLT_MAX; int bi = 0x7fffffff; int bq = 0;
#pragma unroll
        for (int qt = 0; qt < NSL; qt++) {
            float vv = (p[qt] < KNN) ? dl[qt][p[qt]] : FLT_MAX;
            int   ci = (p[qt] < KNN) ? il[qt][p[qt]] : 0x7fffffff;
            if (vv < best || (vv == best && ci < bi)) { best = vv; bi = ci; bq = qt; }
        }
        o[j] = bi;
        p[bq]++;
    }
}

// ---------------------------------------------------------------------------
// Fused q/p MFMA GEMM (edge stages) — unchanged.
// ---------------------------------------------------------------------------
template<int KDP>
__global__ __launch_bounds__(256)
void qp_mfma(const unsigned short* __restrict__ Ghi,
             const unsigned short* __restrict__ Glo,
             const unsigned short* __restrict__ Wqh, const unsigned short* __restrict__ Wql,
             const unsigned short* __restrict__ Wph, const unsigned short* __restrict__ Wpl,
             const float* __restrict__ shf,
             float* __restrict__ qv, float* __restrict__ pv, int cout)
{
    constexpr int KS = KDP / 32;
    int tid = threadIdx.x;
    int w = tid >> 6, L = tid & 63;
    int n = L & 15, quad = L >> 4;
    int b = blockIdx.z;
    int p0 = blockIdx.x * 64 + w * 16;

    s8v ah[KS], al[KS];
    long abase = ((long)b * N_PTS + p0 + n) * KDP + quad * 8;
#pragma unroll
    for (int ks = 0; ks < KS; ks++) {
        ah[ks] = *(const s8v*)&Ghi[abase + ks * 32];
        al[ks] = *(const s8v*)&Glo[abase + ks * 32];
    }

#pragma unroll
    for (int oc4 = 0; oc4 < 4; oc4++) {
        int oc = blockIdx.y * 4 + oc4;
        long wbase = (long)(oc * 16 + n) * KDP + quad * 8;
        f4v aq = {0.f, 0.f, 0.f, 0.f};
        f4v ap = {0.f, 0.f, 0.f, 0.f};
#pragma unroll
        for (int ks = 0; ks < KS; ks++) {
            s8v wh = *(const s8v*)&Wqh[wbase + ks * 32];
            s8v wl = *(const s8v*)&Wql[wbase + ks * 32];
            aq = __builtin_amdgcn_mfma_f32_16x16x32_bf16(ah[ks], wh, aq, 0, 0, 0);
            aq = __builtin_amdgcn_mfma_f32_16x16x32_bf16(ah[ks], wl, aq, 0, 0, 0);
            aq = __builtin_amdgcn_mfma_f32_16x16x32_bf16(al[ks], wh, aq, 0, 0, 0);
            s8v ph = *(const s8v*)&Wph[wbase + ks * 32];
            s8v pl = *(const s8v*)&Wpl[wbase + ks * 32];
            ap = __builtin_amdgcn_mfma_f32_16x16x32_bf16(ah[ks], ph, ap, 0, 0, 0);
            ap = __builtin_amdgcn_mfma_f32_16x16x32_bf16(ah[ks], pl, ap, 0, 0, 0);
            ap = __builtin_amdgcn_mfma_f32_16x16x32_bf16(al[ks], ph, ap, 0, 0, 0);
        }
        float sv = shf[oc * 16 + n];
#pragma unroll
        for (int r = 0; r < 4; r++) {
            long pt = p0 + quad * 4 + r;
            long o = ((long)b * N_PTS + pt) * cout + oc * 16 + n;
            qv[o] = aq[r];
            pv[o] = ap[r] + sv;
        }
    }
}

// ---------------------------------------------------------------------------
// Stage-4 conv with fused global-max (atomicMax on encoded fp32) — R30 win.
// ---------------------------------------------------------------------------
__global__ __launch_bounds__(256)
void conv4h_mfma(const float* __restrict__ cat,
                 const unsigned short* __restrict__ W4h, const unsigned short* __restrict__ W4l,
                 const float* __restrict__ shf, unsigned* __restrict__ ymax_u)
{
    __shared__ short Wbs[2][2][2048];
    __shared__ float Cbs[2][2048];

    int tid = threadIdx.x;
    int w = tid >> 6, L = tid & 63;
    int n = L & 15, quad = L >> 4;
    int b = blockIdx.z;
    int p0b = blockIdx.x * 64;
    int ob0 = blockIdx.y * 64;
    int w64 = tid & 192;

    const char* catb = (const char*)(cat + ((long)b * N_PTS + p0b) * 512);
    const char* whb  = (const char*)(W4h + (long)ob0 * 512);
    const char* wlb  = (const char*)(W4l + (long)ob0 * 512);

    int gw = swz(tid);
    int gc0 = swz(tid);
    int gc1 = swz(tid + 256);

    long woff = (long)(gw >> 2) * 1024 + (gw & 3) * 16;
    long coff0 = (long)(gc0 >> 3) * 2048 + (gc0 & 7) * 16;
    long coff1 = (long)(gc1 >> 3) * 2048 + (gc1 & 7) * 16;

    {
        gl2lds16(whb + woff, (char*)&Wbs[0][0][0] + w64 * 16);
        gl2lds16(wlb + woff, (char*)&Wbs[0][1][0] + w64 * 16);
        gl2lds16(catb + coff0, (char*)&Cbs[0][0] + w64 * 16);
        gl2lds16(catb + coff1, (char*)&Cbs[0][0] + (256 + w64) * 16);
    }
    __syncthreads();

    int p8 = (w * 16 + n) * 8;
    int cch0 = swz(p8 + quad * 2) * 16;
    int cch1 = swz(p8 + quad * 2 + 1) * 16;
    int wch[4];
#pragma unroll
    for (int c4 = 0; c4 < 4; c4++) wch[c4] = swz((c4 * 16 + n) * 4 + quad) * 16;

    f4v acc[4];
#pragma unroll
    for (int c4 = 0; c4 < 4; c4++) acc[c4] = {0.f, 0.f, 0.f, 0.f};

    for (int ks = 0; ks < 16; ks++) {
        int cur = ks & 1;
        if (ks < 15) {
            long t2 = (long)(ks + 1) * 64;
            long tc = (long)(ks + 1) * 128;
            gl2lds16(whb + t2 + woff, (char*)&Wbs[cur ^ 1][0][0] + w64 * 16);
            gl2lds16(wlb + t2 + woff, (char*)&Wbs[cur ^ 1][1][0] + w64 * 16);
            gl2lds16(catb + tc + coff0, (char*)&Cbs[cur ^ 1][0] + w64 * 16);
            gl2lds16(catb + tc + coff1, (char*)&Cbs[cur ^ 1][0] + (256 + w64) * 16);
        }

        float4 c0 = *(const float4*)((const char*)&Cbs[cur][0] + cch0);
        float4 c1 = *(const float4*)((const char*)&Cbs[cur][0] + cch1);
        float fv[8] = {c0.x, c0.y, c0.z, c0.w, c1.x, c1.y, c1.z, c1.w};
        s8v ah, al;
#pragma unroll
        for (int i = 0; i < 8; i++) {
            unsigned short h, l;
            bf16split(fv[i], &h, &l);
            ah[i] = (short)h;
            al[i] = (short)l;
        }
#pragma unroll
        for (int c4 = 0; c4 < 4; c4++) {
            s8v wh = *(const s8v*)((const char*)&Wbs[cur][0][0] + wch[c4]);
            s8v wl = *(const s8v*)((const char*)&Wbs[cur][1][0] + wch[c4]);
            acc[c4] = __builtin_amdgcn_mfma_f32_16x16x32_bf16(ah, wh, acc[c4], 0, 0, 0);
            acc[c4] = __builtin_amdgcn_mfma_f32_16x16x32_bf16(ah, wl, acc[c4], 0, 0, 0);
            acc[c4] = __builtin_amdgcn_mfma_f32_16x16x32_bf16(al, wh, acc[c4], 0, 0, 0);
        }
        __syncthreads();
    }

#pragma unroll
    for (int c4 = 0; c4 < 4; c4++) {
        int o = ob0 + c4 * 16 + n;
        float sv = shf[o];
        float mx = -FLT_MAX;
#pragma unroll
        for (int r = 0; r < 4; r++) {
            float y = acc[c4][r] + sv;
            y = y >= 0.f ? y : 0.2f * y;
            mx = fmaxf(mx, y);
        }
        mx = fmaxf(mx, __shfl_xor(mx, 16));
        mx = fmaxf(mx, __shfl_xor(mx, 32));
        if (quad == 0)
            atomicMax(&ymax_u[(long)b * 512 + o], encf(mx));
    }
}

// ---------------------------------------------------------------------------
// Weight folding to bf16 hi/lo, [o][c] layout.
// ---------------------------------------------------------------------------
__global__ void fold_edge_bf16(const float* __restrict__ W, const float* __restrict__ g,
                               const float* __restrict__ bb, const float* __restrict__ m,
                               const float* __restrict__ v,
                               unsigned short* __restrict__ Wqh, unsigned short* __restrict__ Wql,
                               unsigned short* __restrict__ Wph, unsigned short* __restrict__ Wpl,
                               float* __restrict__ shift, int C, int cout)
{
    int id = blockIdx.x * 256 + threadIdx.x;
    if (id < C * cout) {
        int o = id / C;
        int c = id % C;
        float sc = g[o] * rsqrtf(v[o] + EPSB);
        float wd = W[(long)o * 2 * C + c];
        float wc = W[(long)o * 2 * C + C + c];
        bf16split(sc * wd, &Wqh[id], &Wql[id]);
        bf16split(sc * (wc - wd), &Wph[id], &Wpl[id]);
    }
    if (id < cout) {
        float sc = g[id] * rsqrtf(v[id] + EPSB);
        shift[id] = bb[id] - m[id] * sc;
    }
}

// R30: also zero-inits ymax_u (runs right before conv4h each launch).
__global__ void fold_plain_bf16(const float* __restrict__ W, const float* __restrict__ g,
                                const float* __restrict__ bb, const float* __restrict__ m,
                                const float* __restrict__ v,
                                unsigned short* __restrict__ W4h, unsigned short* __restrict__ W4l,
                                float* __restrict__ shift, unsigned* __restrict__ ymax_u,
                                int C, int cout)
{
    int id = blockIdx.x * 256 + threadIdx.x;
    if (id < C * cout) {
        int o = id / C;
        int c = id % C;
        float sc = g[o] * rsqrtf(v[o] + EPSB);
        bf16split(sc * W[(long)o * C + c], &W4h[id], &W4l[id]);
    }
    if (id < cout) {
        float sc = g[id] * rsqrtf(v[id] + EPSB);
        shift[id] = bb[id] - m[id] * sc;
    }
    if (id < 2048) ymax_u[id] = 0u;   // encf lower bound
}

// ---------------------------------------------------------------------------
// Gather+max writing cat slice AND (optionally) next stage's G arrays + xx.
// ---------------------------------------------------------------------------
__global__ void gather_max_fused(const float* __restrict__ q, const float* __restrict__ p,
                                 const int* __restrict__ idx, float* __restrict__ cat,
                                 int cout, int c_off,
                                 unsigned short* __restrict__ Ghi,
                                 unsigned short* __restrict__ Glo,
                                 float* __restrict__ xx)
{
    int b = blockIdx.y;
    int i = blockIdx.x * 4 + threadIdx.y;
    int tx = threadIdx.x;
    const int* ip = idx + ((long)b * N_PTS + i) * KNN;
    int js[KNN];
#pragma unroll
    for (int k = 0; k < KNN; k++) js[k] = ip[k];
    const float* qb = q + (long)b * N_PTS * cout;
    const float* pb = p + ((long)b * N_PTS + i) * cout;
    float* ob = cat + ((long)b * N_PTS + i) * 512 + c_off;
    float ssum = 0.f;
    for (int o0 = 0; o0 < cout; o0 += 64) {
        int o = o0 + tx;
        float pv = pb[o];
        float mx = -FLT_MAX;
#pragma unroll
        for (int k = 0; k < KNN; k++) {
            float val = qb[(long)js[k] * cout + o] + pv;
            val = val >= 0.f ? val : 0.2f * val;
            mx = fmaxf(mx, val);
        }
        ob[o] = mx;
        if (Ghi) {
            unsigned short h, l;
            bf16split(mx, &h, &l);
            long go = ((long)b * N_PTS + i) * cout + o;
            Ghi[go] = h;
            Glo[go] = l;
            ssum = fmaf(mx, mx, ssum);
        }
    }
    if (Ghi) {
#pragma unroll
        for (int off = 32; off > 0; off >>= 1) ssum += __shfl_xor(ssum, off);
        if (tx == 0) xx[(long)b * N_PTS + i] = ssum;
    }
}

// ---------------------------------------------------------------------------
// Block-0 edge conv (R29 form — parallel merge done by knn_merge4 upstream).
// ---------------------------------------------------------------------------
__global__ void edge0_fused(const float* __restrict__ x, const int* __restrict__ idx,
                            const float* __restrict__ W0, const float* __restrict__ g0,
                            const float* __restrict__ b0, const float* __restrict__ m0,
                            const float* __restrict__ v0, float* __restrict__ cat,
                            unsigned short* __restrict__ Ghi,
                            unsigned short* __restrict__ Glo,
                            float* __restrict__ xx)
{
    int b = blockIdx.y;
    int i = blockIdx.x * 4 + threadIdx.y;
    int o = threadIdx.x;
    const float* xc = x + ((long)b * N_PTS + i) * 3;
    float cx = xc[0], cy = xc[1], cz = xc[2];
    float w[9];
#pragma unroll
    for (int c = 0; c < 9; c++) w[c] = W0[o * 9 + c];
    float sc = g0[o] * rsqrtf(v0[o] + EPSB);
    float sh = b0[o] - m0[o] * sc;
    const int* ip = idx + ((long)b * N_PTS + i) * KNN;
    float mx = -FLT_MAX;
#pragma unroll
    for (int k = 0; k < KNN; k++) {
        const float* xn = x + ((long)b * N_PTS + ip[k]) * 3;
        float nx = xn[0], ny = xn[1], nz = xn[2];
        float dx = nx - cx, dy = ny - cy, dz = nz - cz;
        float crx = cy * nz - cz * ny;
        float cry = cz * nx - cx * nz;
        float crz = cx * ny - cy * nx;
        float y = w[0] * dx + w[1] * dy + w[2] * dz
                + w[3] * crx + w[4] * cry + w[5] * crz
                + w[6] * cx + w[7] * cy + w[8] * cz;
        y = y * sc + sh;
        y = y >= 0.f ? y : 0.2f * y;
        mx = fmaxf(mx, y);
    }
    cat[((long)b * N_PTS + i) * 512 + o] = mx;
    unsigned short h, l;
    bf16split(mx, &h, &l);
    long go = ((long)b * N_PTS + i) * 64 + o;
    Ghi[go] = h;
    Glo[go] = l;
    float ssum = mx * mx;
#pragma unroll
    for (int off = 32; off > 0; off >>= 1) ssum += __shfl_xor(ssum, off);
    if (o == 0) xx[(long)b * N_PTS + i] = ssum;
}

// R30: decodes the atomicMax-encoded ymax.
__global__ void head_kernel(const unsigned* __restrict__ ymax_u, const float* __restrict__ We,
                            const float* __restrict__ Wh, const float* __restrict__ bh,
                            float* __restrict__ out)
{
    __shared__ float emb[128];
    __shared__ float yv[512];
    int b = blockIdx.x, t = threadIdx.x;
    for (int s = t; s < 512; s += 128) yv[s] = decf(ymax_u[(long)b * 512 + s]);
    __syncthreads();
    float acc = 0.f;
    for (int c = 0; c < 512; c++) acc = fmaf(yv[c], We[(long)t * 512 + c], acc);
    emb[t] = acc;
    __syncthreads();
    float acc2 = bh[t];
    for (int ff = 0; ff < 128; ff++) acc2 = fmaf(emb[ff], Wh[(long)t * 128 + ff], acc2);
    out[(long)b * 128 + t] = acc2;
}

// ---------------------------------------------------------------------------
extern "C" void kernel_launch(void* const* d_in, const int* in_sizes, int n_in,
                              void* d_out, int out_size, void* d_ws, size_t ws_size,
                              hipStream_t stream)
{
    const float* x = (const float*)d_in[0];
    const float *W[5], *g[5], *bb[5], *m[5], *v[5];
    for (int li = 0; li < 5; li++) {
        W[li]  = (const float*)d_in[1 + li * 5 + 0];
        g[li]  = (const float*)d_in[1 + li * 5 + 1];
        bb[li] = (const float*)d_in[1 + li * 5 + 2];
        m[li]  = (const float*)d_in[1 + li * 5 + 3];
        v[li]  = (const float*)d_in[1 + li * 5 + 4];
    }
    const float* We = (const float*)d_in[26];
    const float* Wh = (const float*)d_in[27];
    const float* bh = (const float*)d_in[28];
    float* out = (float*)d_out;

    // workspace carve (float units). cat POINT-MAJOR [b][pt][512].
    float* ws   = (float*)d_ws;
    float* cat  = ws;                                   // 8,388,608
    float* qbuf = cat + (long)8388608;                  // 8,388,608 multi-purpose
    float* pbuf = qbuf + (long)8388608;                 // 4,194,304 (p-values)
    int*   idxb = (int*)(pbuf + 4194304);               // 327,680 ints
    float* xx   = (float*)(idxb + 327680);              // 16,384
    unsigned short* Wqh = (unsigned short*)(xx + 16384);// 32,768 shorts each
    unsigned short* Wql = Wqh + 32768;
    unsigned short* Wph = Wql + 32768;
    unsigned short* Wpl = Wph + 32768;
    unsigned short* W4h = Wpl + 32768;                  // 262,144 shorts
    unsigned short* W4l = W4h + 262144;
    float* shf  = (float*)(W4l + 262144);               // 512
    unsigned* ymax_u = (unsigned*)(shf + 512);          // 2,048 (encoded fp32)
    unsigned short* Ghi = (unsigned short*)qbuf;        // 2,097,152 shorts max
    unsigned short* Glo = Ghi + 2097152;
    float* knnd = qbuf + 2097152;                       // 1,310,720 floats
    int*   knni = (int*)(qbuf + 2097152 + 1310720);     // 1,310,720 ints
    float* qv   = qbuf + 2097152;                       // 4,194,304 floats (after knn)

    // ---- stage 0: knn on coords, straight from x ----
    prep0<<<dim3(16, NB), dim3(256), 0, stream>>>(x, xx, Ghi, Glo);
    fused_knn_mfma13<32><<<dim3(32 * NSL * NB), dim3(256), 0, stream>>>(
        Ghi, Glo, xx, knnd, knni);
    knn_merge4<<<dim3(64), dim3(256), 0, stream>>>(knnd, knni, idxb);
    edge0_fused<<<dim3(N_PTS / 4, NB), dim3(64, 4), 0, stream>>>(
        x, idxb, W[0], g[0], bb[0], m[0], v[0], cat, Ghi, Glo, xx);

    // ---- stages 1..3 ----
    const int Cs_[3]   = {64, 64, 128};
    const int co_[3]   = {64, 128, 256};
    const int outO_[3] = {64, 128, 256};
    for (int s = 0; s < 3; s++) {
        int C = Cs_[s], cout = co_[s];
        if (C == 64)
            fused_knn_mfma13<64><<<dim3(32 * NSL * NB), dim3(256), 0, stream>>>(
                Ghi, Glo, xx, knnd, knni);
        else
            fused_knn_mfma13<128><<<dim3(32 * NSL * NB), dim3(256), 0, stream>>>(
                Ghi, Glo, xx, knnd, knni);
        knn_merge4<<<dim3(64), dim3(256), 0, stream>>>(knnd, knni, idxb);

        int li = s + 1;
        fold_edge_bf16<<<dim3((C * cout + 255) / 256), dim3(256), 0, stream>>>(
            W[li], g[li], bb[li], m[li], v[li], Wqh, Wql, Wph, Wpl, shf, C, cout);
        if (C == 64)
            qp_mfma<64><<<dim3(64, cout / 64, NB), dim3(256), 0, stream>>>(
                Ghi, Glo, Wqh, Wql, Wph, Wpl, shf, qv, pbuf, cout);
        else
            qp_mfma<128><<<dim3(64, cout / 64, NB), dim3(256), 0, stream>>>(
                Ghi, Glo, Wqh, Wql, Wph, Wpl, shf, qv, pbuf, cout);
        if (s < 2)
            gather_max_fused<<<dim3(N_PTS / 4, NB), dim3(64, 4), 0, stream>>>(
                qv, pbuf, idxb, cat, cout, outO_[s], Ghi, Glo, xx);
        else
            gather_max_fused<<<dim3(N_PTS / 4, NB), dim3(64, 4), 0, stream>>>(
                qv, pbuf, idxb, cat, cout, outO_[s],
                (unsigned short*)nullptr, (unsigned short*)nullptr, (float*)nullptr);
    }

    // ---- stage 4: LDS-staged MFMA conv with fused global-max (atomic) ----
    fold_plain_bf16<<<dim3((512 * 512 + 255) / 256), dim3(256), 0, stream>>>(
        W[4], g[4], bb[4], m[4], v[4], W4h, W4l, shf, ymax_u, 512, 512);
    conv4h_mfma<<<dim3(N_PTS / 64, 8, NB), dim3(256), 0, stream>>>(
        cat, W4h, W4l, shf, ymax_u);

    // ---- head ----
    head_kernel<<<dim3(NB), dim3(128), 0, stream>>>(ymax_u, We, Wh, bh, out);
}

// Round 11
// 748.497 us; speedup vs baseline: 1.0900x; 1.0900x over previous
//
#include <hip/hip_runtime.h>
#include <cfloat>

#define N_PTS 4096
#define NB    4
#define KNN   20
#define EPSB  1e-5f
#define NSL   4          // knn candidate slices per batch-row (R22: NSL=8 regressed net)

typedef short s8v __attribute__((ext_vector_type(8)));
typedef float f4v __attribute__((ext_vector_type(4)));

// ---------------------------------------------------------------------------
// bf16 hi/lo split (round-to-nearest-even both halves)
// ---------------------------------------------------------------------------
__device__ __forceinline__ void bf16split(float x, unsigned short* h, unsigned short* l)
{
    unsigned u = __builtin_bit_cast(unsigned, x);
    unsigned hb = (u + 0x7fffu + ((u >> 16) & 1u)) >> 16;
    float hf = __builtin_bit_cast(float, hb << 16);
    float res = x - hf;
    unsigned u2 = __builtin_bit_cast(unsigned, res);
    unsigned lb = (u2 + 0x7fffu + ((u2 >> 16) & 1u)) >> 16;
    *h = (unsigned short)hb;
    *l = (unsigned short)lb;
}

// ---------------------------------------------------------------------------
// Packed key: fp32 distance (top 24 bits) | 8-bit lane-local ordinal.
// ---------------------------------------------------------------------------
__device__ __forceinline__ unsigned packkey(float d, int lc)
{
    d = fmaxf(d, 0.f);
    unsigned u = __builtin_bit_cast(unsigned, d);
    return (u & 0xFFFFFF00u) | (unsigned)lc;
}

// compare-exchange: a=min, b=max  (v_min_u32 + v_max_u32)
__device__ __forceinline__ void ce(unsigned& a, unsigned& b)
{
    unsigned lo = a < b ? a : b;
    b = a < b ? b : a;
    a = lo;
}

// ---------------------------------------------------------------------------
// R25 batch-8 top-20 maintenance (verified): Batcher sort-8 + half-clean +
// bitonic-8 tail + Batcher odd-even merge(12,8) + canonicalize.
// ---------------------------------------------------------------------------
__device__ __forceinline__ void insert8k(unsigned c0, unsigned c1, unsigned c2, unsigned c3,
                                         unsigned c4, unsigned c5, unsigned c6, unsigned c7,
                                         unsigned (&k)[KNN])
{
    ce(c0, c1); ce(c2, c3); ce(c0, c2); ce(c1, c3); ce(c1, c2);
    ce(c4, c5); ce(c6, c7); ce(c4, c6); ce(c5, c7); ce(c5, c6);
    ce(c0, c4); ce(c2, c6); ce(c2, c4);
    ce(c1, c5); ce(c3, c7); ce(c3, c5);
    ce(c1, c2); ce(c3, c4); ce(c5, c6);
    k[12] = k[12] < c7 ? k[12] : c7;
    k[13] = k[13] < c6 ? k[13] : c6;
    k[14] = k[14] < c5 ? k[14] : c5;
    k[15] = k[15] < c4 ? k[15] : c4;
    k[16] = k[16] < c3 ? k[16] : c3;
    k[17] = k[17] < c2 ? k[17] : c2;
    k[18] = k[18] < c1 ? k[18] : c1;
    k[19] = k[19] < c0 ? k[19] : c0;
    ce(k[12], k[16]); ce(k[13], k[17]); ce(k[14], k[18]); ce(k[15], k[19]);
    ce(k[12], k[14]); ce(k[13], k[15]); ce(k[16], k[18]); ce(k[17], k[19]);
    ce(k[12], k[13]); ce(k[14], k[15]); ce(k[16], k[17]); ce(k[18], k[19]);
    ce(k[0],  k[12]); ce(k[8],  k[12]); ce(k[4],  k[16]); ce(k[4],  k[8]);  ce(k[16], k[12]);
    ce(k[2],  k[14]); ce(k[10], k[14]); ce(k[6],  k[18]); ce(k[6],  k[10]); ce(k[18], k[14]);
    ce(k[2],  k[4]);  ce(k[6],  k[8]);  ce(k[10], k[16]); ce(k[18], k[12]);
    ce(k[1],  k[13]); ce(k[9],  k[13]); ce(k[5],  k[17]); ce(k[5],  k[9]);  ce(k[17], k[13]);
    ce(k[3],  k[15]); ce(k[11], k[15]); ce(k[7],  k[19]); ce(k[7],  k[11]); ce(k[19], k[15]);
    ce(k[3],  k[5]);  ce(k[7],  k[9]);  ce(k[11], k[17]); ce(k[19], k[13]);
    ce(k[1],  k[2]);  ce(k[3],  k[4]);  ce(k[5],  k[6]);  ce(k[7],  k[8]);  ce(k[9], k[10]);
    ce(k[11], k[16]); ce(k[17], k[18]); ce(k[19], k[12]); ce(k[13], k[14]);
    unsigned s;
    s = k[12]; k[12] = k[16]; k[16] = s;
    s = k[13]; k[13] = k[17]; k[17] = s;
    s = k[14]; k[14] = k[18]; k[18] = s;
    s = k[15]; k[15] = k[19]; k[19] = s;
}

// async global->LDS, 16B per lane; LDS dest = wave-uniform base + lane*16
__device__ __forceinline__ void gl2lds16(const void* g, void* l)
{
    __builtin_amdgcn_global_load_lds(
        (const __attribute__((address_space(1))) unsigned int*)g,
        (__attribute__((address_space(3))) unsigned int*)l,
        16, 0, 0);
}

// 16B-chunk swizzle (involution): chunk g lives at LDS chunk g ^ f(g).
__device__ __forceinline__ int swz(int g)
{
    return g ^ (((g >> 3) ^ (g >> 6)) & 7);
}

// monotone fp32 <-> u32 order-preserving encode (for atomicMax reduction)
__device__ __forceinline__ unsigned encf(float f)
{
    unsigned u = __builtin_bit_cast(unsigned, f);
    return (u & 0x80000000u) ? ~u : (u | 0x80000000u);
}
__device__ __forceinline__ float decf(unsigned u)
{
    return (u & 0x80000000u) ? __builtin_bit_cast(float, u ^ 0x80000000u)
                             : __builtin_bit_cast(float, ~u);
}

// ---------------------------------------------------------------------------
// R30: fused stage-0 prep (verified win).
// ---------------------------------------------------------------------------
__global__ __launch_bounds__(256)
void prep0(const float* __restrict__ x, float* __restrict__ xx,
           unsigned short* __restrict__ Ghi, unsigned short* __restrict__ Glo)
{
    int b = blockIdx.y;
    int i = blockIdx.x * 256 + threadIdx.x;
    const float* r = x + ((long)b * N_PTS + i) * 3;
    float v0 = r[0], v1 = r[1], v2 = r[2];
    float s = 0.f;
    s = fmaf(v0, v0, s);
    s = fmaf(v1, v1, s);
    s = fmaf(v2, v2, s);
    xx[(long)b * N_PTS + i] = s;

    float cv[3] = {v0, v1, v2};
    long o = ((long)b * N_PTS + i) * 32;
#pragma unroll
    for (int q = 0; q < 4; q++) {
        s8v hv, lv;
#pragma unroll
        for (int e = 0; e < 8; e++) {
            int k = q * 8 + e;
            float xv = (k < 3) ? cv[k] : 0.f;
            unsigned short h, l;
            bf16split(xv, &h, &l);
            hv[e] = (short)h;
            lv[e] = (short)l;
        }
        *(s8v*)&Ghi[o + q * 8] = hv;
        *(s8v*)&Glo[o + q * 8] = lv;
    }
}

// ---------------------------------------------------------------------------
// R31-best knn (R25 structure + XCD mapping + mk@21). Declared plateau.
// ---------------------------------------------------------------------------
template<int KDP>
__global__ __launch_bounds__(256, 4)
void fused_knn_mfma12(const unsigned short* __restrict__ Ghi,
                      const unsigned short* __restrict__ Glo,
                      const float* __restrict__ xx,
                      float* __restrict__ knnd, int* __restrict__ knni)
{
    constexpr int KS = KDP / 32;
    constexpr int TS = 16 * KDP;
    constexpr int NCH2 = 4 * KDP;
    __shared__ union ShU {
        short cb[2][2][2 * TS];
        unsigned mk[4][16][4][21];
    } sh;

    int tid = threadIdx.x;
    int w = tid >> 6, L = tid & 63;
    int n = L & 15;
    int quad = L >> 4;

    int bid = blockIdx.x;
    int xcd = bid & 7;
    int slot = bid >> 3;
    int g = xcd + (slot >> 6) * 8;
    int qt = slot & 63;
    int slice = g & 3;
    int b = g >> 2;

    int q0 = qt * 64, qw = w * 16;
    const unsigned short* Gh = Ghi + (long)b * N_PTS * KDP;
    const unsigned short* Gl = Glo + (long)b * N_PTS * KDP;
    const float* xxb = xx + (long)b * N_PTS;

    s8v qhi[KS], qlo[KS];
    long qbase = (long)(q0 + qw + n) * KDP + quad * 8;
#pragma unroll
    for (int ks = 0; ks < KS; ks++) {
        qhi[ks] = *(const s8v*)&Gh[qbase + ks * 32];
        qlo[ks] = *(const s8v*)&Gl[qbase + ks * 32];
    }
    float xq = xxb[q0 + qw + n];

    unsigned k20[KNN];
#pragma unroll
    for (int j = 0; j < KNN; j++) k20[j] = 0xFFFFFFFFu;

    int poA[KS], poB[KS];
#pragma unroll
    for (int ks = 0; ks < KS; ks++) {
        int gL = n * (KDP / 8) + quad + ks * 4;
        poA[ks] = swz(gL) * 8;
        poB[ks] = swz(gL + 2 * KDP) * 8;
    }
    int gsrc = swz(tid);
    int w64 = tid & 192;

    {
        long tb = (long)(slice * 1024) * KDP;
        if (tid < NCH2) {
            gl2lds16((const char*)(Gh + tb) + gsrc * 16,
                     (char*)&sh.cb[0][0][0] + w64 * 16);
            gl2lds16((const char*)(Gl + tb) + gsrc * 16,
                     (char*)&sh.cb[0][1][0] + w64 * 16);
        }
        if constexpr (NCH2 == 512) {
            int gsrc2 = swz(tid + 256);
            gl2lds16((const char*)(Gh + tb) + gsrc2 * 16,
                     (char*)&sh.cb[0][0][0] + (256 + w64) * 16);
            gl2lds16((const char*)(Gl + tb) + gsrc2 * 16,
                     (char*)&sh.cb[0][1][0] + (256 + w64) * 16);
        }
    }
    __syncthreads();

    const float* xcp = xxb + slice * 1024 + quad * 4;

    for (int it = 0; it < 32; it++) {
        int cur = it & 1;
        if (it < 31) {
            long tb = (long)(slice * 1024 + (it + 1) * 32) * KDP;
            if (tid < NCH2) {
                gl2lds16((const char*)(Gh + tb) + gsrc * 16,
                         (char*)&sh.cb[cur ^ 1][0][0] + w64 * 16);
                gl2lds16((const char*)(Gl + tb) + gsrc * 16,
                         (char*)&sh.cb[cur ^ 1][1][0] + w64 * 16);
            }
            if constexpr (NCH2 == 512) {
                int gsrc2 = swz(tid + 256);
                gl2lds16((const char*)(Gh + tb) + gsrc2 * 16,
                         (char*)&sh.cb[cur ^ 1][0][0] + (256 + w64) * 16);
                gl2lds16((const char*)(Gl + tb) + gsrc2 * 16,
                         (char*)&sh.cb[cur ^ 1][1][0] + (256 + w64) * 16);
            }
        }

        const short* Ch = &sh.cb[cur][0][0];
        const short* Cl = &sh.cb[cur][1][0];
        f4v accA = {0.f, 0.f, 0.f, 0.f};
        f4v accB = {0.f, 0.f, 0.f, 0.f};
#pragma unroll
        for (int ks = 0; ks < KS; ks++) {
            s8v chiA = *(const s8v*)&Ch[poA[ks]];
            s8v cloA = *(const s8v*)&Cl[poA[ks]];
            accA = __builtin_amdgcn_mfma_f32_16x16x32_bf16(chiA, qhi[ks], accA, 0, 0, 0);
            accA = __builtin_amdgcn_mfma_f32_16x16x32_bf16(chiA, qlo[ks], accA, 0, 0, 0);
            accA = __builtin_amdgcn_mfma_f32_16x16x32_bf16(cloA, qhi[ks], accA, 0, 0, 0);
            s8v chiB = *(const s8v*)&Ch[poB[ks]];
            s8v cloB = *(const s8v*)&Cl[poB[ks]];
            accB = __builtin_amdgcn_mfma_f32_16x16x32_bf16(chiB, qhi[ks], accB, 0, 0, 0);
            accB = __builtin_amdgcn_mfma_f32_16x16x32_bf16(chiB, qlo[ks], accB, 0, 0, 0);
            accB = __builtin_amdgcn_mfma_f32_16x16x32_bf16(cloB, qhi[ks], accB, 0, 0, 0);
        }
        float4 xcA = *(const float4*)xcp;
        float4 xcB = *(const float4*)(xcp + 16);
        float xavA[4] = {xcA.x, xcA.y, xcA.z, xcA.w};
        float xavB[4] = {xcB.x, xcB.y, xcB.z, xcB.w};
        unsigned c[8];
#pragma unroll
        for (int r = 0; r < 4; r++) {
            float dA = xq + xavA[r] - 2.f * accA[r];
            float dB = xq + xavB[r] - 2.f * accB[r];
            c[r]     = packkey(dA, it * 8 + r);
            c[4 + r] = packkey(dB, it * 8 + 4 + r);
        }
        insert8k(c[0], c[1], c[2], c[3], c[4], c[5], c[6], c[7], k20);
        xcp += 32;
        __syncthreads();
    }

#pragma unroll
    for (int j = 0; j < KNN; j++) sh.mk[w][n][quad][j] = k20[j];
    __syncthreads();
    if (L < 16) {
        int p[4] = {0, 0, 0, 0};
        long o = (((long)b * NSL + slice) * N_PTS + (q0 + qw + L)) * KNN;
#pragma unroll
        for (int j = 0; j < KNN; j++) {
            unsigned bd = 0xFFFFFF00u; int bi = 0x7fffffff; int bq = 0;
#pragma unroll
            for (int qd = 0; qd < 4; qd++) {
                unsigned kk = sh.mk[w][L][qd][p[qd]];
                unsigned db = kk & 0xFFFFFF00u;
                int lc = (int)(kk & 0xFFu);
                int ci = slice * 1024 + (lc >> 2) * 16 + qd * 4 + (lc & 3);
                if (db < bd || (db == bd && ci < bi)) { bd = db; bi = ci; bq = qd; }
            }
            knnd[o + j] = __builtin_bit_cast(float, bd);
            knni[o + j] = bi;
            p[bq]++;
        }
    }
}

// ---------------------------------------------------------------------------
__global__ void knn_merge4(const float* __restrict__ knnd, const int* __restrict__ knni,
                           int* __restrict__ idxOut)
{
    int id = blockIdx.x * 256 + threadIdx.x;
    int b = id / N_PTS, i = id % N_PTS;
    const float* dl[NSL]; const int* il[NSL];
#pragma unroll
    for (int qt = 0; qt < NSL; qt++) {
        dl[qt] = knnd + (((long)b * NSL + qt) * N_PTS + i) * KNN;
        il[qt] = knni + (((long)b * NSL + qt) * N_PTS + i) * KNN;
    }
    int p[NSL];
#pragma unroll
    for (int qt = 0; qt < NSL; qt++) p[qt] = 0;
    int* o = idxOut + (long)id * KNN;
#pragma unroll
    for (int j = 0; j < KNN; j++) {
        float best = FLT_MAX; int bi = 0x7fffffff; int bq = 0;
#pragma unroll
        for (int qt = 0; qt < NSL; qt++) {
            float vv = (p[qt] < KNN) ? dl[qt][p[qt]] : FLT_MAX;
            int   ci = (p[qt] < KNN) ? il[qt][p[qt]] : 0x7fffffff;
            if (vv < best || (vv == best && ci < bi)) { best = vv; bi = ci; bq = qt; }
        }
        o[j] = bi;
        p[bq]++;
    }
}

// ---------------------------------------------------------------------------
// Fused q/p MFMA GEMM (edge stages) — unchanged.
// ---------------------------------------------------------------------------
template<int KDP>
__global__ __launch_bounds__(256)
void qp_mfma(const unsigned short* __restrict__ Ghi,
             const unsigned short* __restrict__ Glo,
             const unsigned short* __restrict__ Wqh, const unsigned short* __restrict__ Wql,
             const unsigned short* __restrict__ Wph, const unsigned short* __restrict__ Wpl,
             const float* __restrict__ shf,
             float* __restrict__ qv, float* __restrict__ pv, int cout)
{
    constexpr int KS = KDP / 32;
    int tid = threadIdx.x;
    int w = tid >> 6, L = tid & 63;
    int n = L & 15, quad = L >> 4;
    int b = blockIdx.z;
    int p0 = blockIdx.x * 64 + w * 16;

    s8v ah[KS], al[KS];
    long abase = ((long)b * N_PTS + p0 + n) * KDP + quad * 8;
#pragma unroll
    for (int ks = 0; ks < KS; ks++) {
        ah[ks] = *(const s8v*)&Ghi[abase + ks * 32];
        al[ks] = *(const s8v*)&Glo[abase + ks * 32];
    }

#pragma unroll
    for (int oc4 = 0; oc4 < 4; oc4++) {
        int oc = blockIdx.y * 4 + oc4;
        long wbase = (long)(oc * 16 + n) * KDP + quad * 8;
        f4v aq = {0.f, 0.f, 0.f, 0.f};
        f4v ap = {0.f, 0.f, 0.f, 0.f};
#pragma unroll
        for (int ks = 0; ks < KS; ks++) {
            s8v wh = *(const s8v*)&Wqh[wbase + ks * 32];
            s8v wl = *(const s8v*)&Wql[wbase + ks * 32];
            aq = __builtin_amdgcn_mfma_f32_16x16x32_bf16(ah[ks], wh, aq, 0, 0, 0);
            aq = __builtin_amdgcn_mfma_f32_16x16x32_bf16(ah[ks], wl, aq, 0, 0, 0);
            aq = __builtin_amdgcn_mfma_f32_16x16x32_bf16(al[ks], wh, aq, 0, 0, 0);
            s8v ph = *(const s8v*)&Wph[wbase + ks * 32];
            s8v pl = *(const s8v*)&Wpl[wbase + ks * 32];
            ap = __builtin_amdgcn_mfma_f32_16x16x32_bf16(ah[ks], ph, ap, 0, 0, 0);
            ap = __builtin_amdgcn_mfma_f32_16x16x32_bf16(ah[ks], pl, ap, 0, 0, 0);
            ap = __builtin_amdgcn_mfma_f32_16x16x32_bf16(al[ks], ph, ap, 0, 0, 0);
        }
        float sv = shf[oc * 16 + n];
#pragma unroll
        for (int r = 0; r < 4; r++) {
            long pt = p0 + quad * 4 + r;
            long o = ((long)b * N_PTS + pt) * cout + oc * 16 + n;
            qv[o] = aq[r];
            pv[o] = ap[r] + sv;
        }
    }
}

// ---------------------------------------------------------------------------
// Stage-4 conv with fused global-max (R30 win) + R33 XCD grouping:
// the 8 ob-blocks of each (b,p0b) cat-tile land on ONE XCD (adjacent
// dispatch slots) -> 7/8 tile reads are L2 hits (cat re-read was 27MB FETCH).
// ---------------------------------------------------------------------------
__global__ __launch_bounds__(256)
void conv4h_mfma(const float* __restrict__ cat,
                 const unsigned short* __restrict__ W4h, const unsigned short* __restrict__ W4l,
                 const float* __restrict__ shf, unsigned* __restrict__ ymax_u)
{
    __shared__ short Wbs[2][2][2048];
    __shared__ float Cbs[2][2048];

    int tid = threadIdx.x;
    int w = tid >> 6, L = tid & 63;
    int n = L & 15, quad = L >> 4;

    // XCD decode: 2048 blocks; group gg=(b,p0b) has its 8 ob-blocks at
    // bid%8==gg%8 with consecutive slots (co-resident on one XCD).
    int bid = blockIdx.x;
    int xcd = bid & 7;
    int s = bid >> 3;          // 0..255
    int gidx = s >> 3;         // 0..31
    int ob = s & 7;
    int gg = xcd + gidx * 8;   // 0..255
    int b = gg >> 6;
    int p0b = (gg & 63) * 64;
    int ob0 = ob * 64;
    int w64 = tid & 192;

    const char* catb = (const char*)(cat + ((long)b * N_PTS + p0b) * 512);
    const char* whb  = (const char*)(W4h + (long)ob0 * 512);
    const char* wlb  = (const char*)(W4l + (long)ob0 * 512);

    int gw = swz(tid);
    int gc0 = swz(tid);
    int gc1 = swz(tid + 256);

    long woff = (long)(gw >> 2) * 1024 + (gw & 3) * 16;
    long coff0 = (long)(gc0 >> 3) * 2048 + (gc0 & 7) * 16;
    long coff1 = (long)(gc1 >> 3) * 2048 + (gc1 & 7) * 16;

    {
        gl2lds16(whb + woff, (char*)&Wbs[0][0][0] + w64 * 16);
        gl2lds16(wlb + woff, (char*)&Wbs[0][1][0] + w64 * 16);
        gl2lds16(catb + coff0, (char*)&Cbs[0][0] + w64 * 16);
        gl2lds16(catb + coff1, (char*)&Cbs[0][0] + (256 + w64) * 16);
    }
    __syncthreads();

    int p8 = (w * 16 + n) * 8;
    int cch0 = swz(p8 + quad * 2) * 16;
    int cch1 = swz(p8 + quad * 2 + 1) * 16;
    int wch[4];
#pragma unroll
    for (int c4 = 0; c4 < 4; c4++) wch[c4] = swz((c4 * 16 + n) * 4 + quad) * 16;

    f4v acc[4];
#pragma unroll
    for (int c4 = 0; c4 < 4; c4++) acc[c4] = {0.f, 0.f, 0.f, 0.f};

    for (int ks = 0; ks < 16; ks++) {
        int cur = ks & 1;
        if (ks < 15) {
            long t2 = (long)(ks + 1) * 64;
            long tc = (long)(ks + 1) * 128;
            gl2lds16(whb + t2 + woff, (char*)&Wbs[cur ^ 1][0][0] + w64 * 16);
            gl2lds16(wlb + t2 + woff, (char*)&Wbs[cur ^ 1][1][0] + w64 * 16);
            gl2lds16(catb + tc + coff0, (char*)&Cbs[cur ^ 1][0] + w64 * 16);
            gl2lds16(catb + tc + coff1, (char*)&Cbs[cur ^ 1][0] + (256 + w64) * 16);
        }

        float4 c0 = *(const float4*)((const char*)&Cbs[cur][0] + cch0);
        float4 c1 = *(const float4*)((const char*)&Cbs[cur][0] + cch1);
        float fv[8] = {c0.x, c0.y, c0.z, c0.w, c1.x, c1.y, c1.z, c1.w};
        s8v ah, al;
#pragma unroll
        for (int i = 0; i < 8; i++) {
            unsigned short h, l;
            bf16split(fv[i], &h, &l);
            ah[i] = (short)h;
            al[i] = (short)l;
        }
#pragma unroll
        for (int c4 = 0; c4 < 4; c4++) {
            s8v wh = *(const s8v*)((const char*)&Wbs[cur][0][0] + wch[c4]);
            s8v wl = *(const s8v*)((const char*)&Wbs[cur][1][0] + wch[c4]);
            acc[c4] = __builtin_amdgcn_mfma_f32_16x16x32_bf16(ah, wh, acc[c4], 0, 0, 0);
            acc[c4] = __builtin_amdgcn_mfma_f32_16x16x32_bf16(ah, wl, acc[c4], 0, 0, 0);
            acc[c4] = __builtin_amdgcn_mfma_f32_16x16x32_bf16(al, wh, acc[c4], 0, 0, 0);
        }
        __syncthreads();
    }

#pragma unroll
    for (int c4 = 0; c4 < 4; c4++) {
        int o = ob0 + c4 * 16 + n;
        float sv = shf[o];
        float mx = -FLT_MAX;
#pragma unroll
        for (int r = 0; r < 4; r++) {
            float y = acc[c4][r] + sv;
            y = y >= 0.f ? y : 0.2f * y;
            mx = fmaxf(mx, y);
        }
        mx = fmaxf(mx, __shfl_xor(mx, 16));
        mx = fmaxf(mx, __shfl_xor(mx, 32));
        if (quad == 0)
            atomicMax(&ymax_u[(long)b * 512 + o], encf(mx));
    }
}

// ---------------------------------------------------------------------------
// Weight folding to bf16 hi/lo, [o][c] layout.
// ---------------------------------------------------------------------------
__global__ void fold_edge_bf16(const float* __restrict__ W, const float* __restrict__ g,
                               const float* __restrict__ bb, const float* __restrict__ m,
                               const float* __restrict__ v,
                               unsigned short* __restrict__ Wqh, unsigned short* __restrict__ Wql,
                               unsigned short* __restrict__ Wph, unsigned short* __restrict__ Wpl,
                               float* __restrict__ shift, int C, int cout)
{
    int id = blockIdx.x * 256 + threadIdx.x;
    if (id < C * cout) {
        int o = id / C;
        int c = id % C;
        float sc = g[o] * rsqrtf(v[o] + EPSB);
        float wd = W[(long)o * 2 * C + c];
        float wc = W[(long)o * 2 * C + C + c];
        bf16split(sc * wd, &Wqh[id], &Wql[id]);
        bf16split(sc * (wc - wd), &Wph[id], &Wpl[id]);
    }
    if (id < cout) {
        float sc = g[id] * rsqrtf(v[id] + EPSB);
        shift[id] = bb[id] - m[id] * sc;
    }
}

// R30: also zero-inits ymax_u (runs right before conv4h each launch).
__global__ void fold_plain_bf16(const float* __restrict__ W, const float* __restrict__ g,
                                const float* __restrict__ bb, const float* __restrict__ m,
                                const float* __restrict__ v,
                                unsigned short* __restrict__ W4h, unsigned short* __restrict__ W4l,
                                float* __restrict__ shift, unsigned* __restrict__ ymax_u,
                                int C, int cout)
{
    int id = blockIdx.x * 256 + threadIdx.x;
    if (id < C * cout) {
        int o = id / C;
        int c = id % C;
        float sc = g[o] * rsqrtf(v[o] + EPSB);
        bf16split(sc * W[(long)o * C + c], &W4h[id], &W4l[id]);
    }
    if (id < cout) {
        float sc = g[id] * rsqrtf(v[id] + EPSB);
        shift[id] = bb[id] - m[id] * sc;
    }
    if (id < 2048) ymax_u[id] = 0u;   // encf lower bound
}

// ---------------------------------------------------------------------------
// Gather+max. R33: 1-D grid with XCD decode — batch b pinned to XCDs
// {b, b+4} so each XCD's neighbor-gather working set is ONE batch's qv
// (<=4MB, L2-resident) instead of all 4 batches (16MB thrash).
// ---------------------------------------------------------------------------
__global__ void gather_max_fused(const float* __restrict__ q, const float* __restrict__ p,
                                 const int* __restrict__ idx, float* __restrict__ cat,
                                 int cout, int c_off,
                                 unsigned short* __restrict__ Ghi,
                                 unsigned short* __restrict__ Glo,
                                 float* __restrict__ xx)
{
    int bid = blockIdx.x;
    int xcd = bid & 7;
    int b = xcd & 3;
    int half = xcd >> 2;
    int slot = bid >> 3;                 // 0..511
    int i = (half * 512 + slot) * 4 + threadIdx.y;
    int tx = threadIdx.x;
    const int* ip = idx + ((long)b * N_PTS + i) * KNN;
    int js[KNN];
#pragma unroll
    for (int k = 0; k < KNN; k++) js[k] = ip[k];
    const float* qb = q + (long)b * N_PTS * cout;
    const float* pb = p + ((long)b * N_PTS + i) * cout;
    float* ob = cat + ((long)b * N_PTS + i) * 512 + c_off;
    float ssum = 0.f;
    for (int o0 = 0; o0 < cout; o0 += 64) {
        int o = o0 + tx;
        float pv = pb[o];
        float mx = -FLT_MAX;
#pragma unroll
        for (int k = 0; k < KNN; k++) {
            float val = qb[(long)js[k] * cout + o] + pv;
            val = val >= 0.f ? val : 0.2f * val;
            mx = fmaxf(mx, val);
        }
        ob[o] = mx;
        if (Ghi) {
            unsigned short h, l;
            bf16split(mx, &h, &l);
            long go = ((long)b * N_PTS + i) * cout + o;
            Ghi[go] = h;
            Glo[go] = l;
            ssum = fmaf(mx, mx, ssum);
        }
    }
    if (Ghi) {
#pragma unroll
        for (int off = 32; off > 0; off >>= 1) ssum += __shfl_xor(ssum, off);
        if (tx == 0) xx[(long)b * N_PTS + i] = ssum;
    }
}

// ---------------------------------------------------------------------------
// Block-0 edge conv (R29 form — parallel merge done by knn_merge4 upstream).
// ---------------------------------------------------------------------------
__global__ void edge0_fused(const float* __restrict__ x, const int* __restrict__ idx,
                            const float* __restrict__ W0, const float* __restrict__ g0,
                            const float* __restrict__ b0, const float* __restrict__ m0,
                            const float* __restrict__ v0, float* __restrict__ cat,
                            unsigned short* __restrict__ Ghi,
                            unsigned short* __restrict__ Glo,
                            float* __restrict__ xx)
{
    int b = blockIdx.y;
    int i = blockIdx.x * 4 + threadIdx.y;
    int o = threadIdx.x;
    const float* xc = x + ((long)b * N_PTS + i) * 3;
    float cx = xc[0], cy = xc[1], cz = xc[2];
    float w[9];
#pragma unroll
    for (int c = 0; c < 9; c++) w[c] = W0[o * 9 + c];
    float sc = g0[o] * rsqrtf(v0[o] + EPSB);
    float sh = b0[o] - m0[o] * sc;
    const int* ip = idx + ((long)b * N_PTS + i) * KNN;
    float mx = -FLT_MAX;
#pragma unroll
    for (int k = 0; k < KNN; k++) {
        const float* xn = x + ((long)b * N_PTS + ip[k]) * 3;
        float nx = xn[0], ny = xn[1], nz = xn[2];
        float dx = nx - cx, dy = ny - cy, dz = nz - cz;
        float crx = cy * nz - cz * ny;
        float cry = cz * nx - cx * nz;
        float crz = cx * ny - cy * nx;
        float y = w[0] * dx + w[1] * dy + w[2] * dz
                + w[3] * crx + w[4] * cry + w[5] * crz
                + w[6] * cx + w[7] * cy + w[8] * cz;
        y = y * sc + sh;
        y = y >= 0.f ? y : 0.2f * y;
        mx = fmaxf(mx, y);
    }
    cat[((long)b * N_PTS + i) * 512 + o] = mx;
    unsigned short h, l;
    bf16split(mx, &h, &l);
    long go = ((long)b * N_PTS + i) * 64 + o;
    Ghi[go] = h;
    Glo[go] = l;
    float ssum = mx * mx;
#pragma unroll
    for (int off = 32; off > 0; off >>= 1) ssum += __shfl_xor(ssum, off);
    if (o == 0) xx[(long)b * N_PTS + i] = ssum;
}

// R30: decodes the atomicMax-encoded ymax.
__global__ void head_kernel(const unsigned* __restrict__ ymax_u, const float* __restrict__ We,
                            const float* __restrict__ Wh, const float* __restrict__ bh,
                            float* __restrict__ out)
{
    __shared__ float emb[128];
    __shared__ float yv[512];
    int b = blockIdx.x, t = threadIdx.x;
    for (int s = t; s < 512; s += 128) yv[s] = decf(ymax_u[(long)b * 512 + s]);
    __syncthreads();
    float acc = 0.f;
    for (int c = 0; c < 512; c++) acc = fmaf(yv[c], We[(long)t * 512 + c], acc);
    emb[t] = acc;
    __syncthreads();
    float acc2 = bh[t];
    for (int ff = 0; ff < 128; ff++) acc2 = fmaf(emb[ff], Wh[(long)t * 128 + ff], acc2);
    out[(long)b * 128 + t] = acc2;
}

// ---------------------------------------------------------------------------
extern "C" void kernel_launch(void* const* d_in, const int* in_sizes, int n_in,
                              void* d_out, int out_size, void* d_ws, size_t ws_size,
                              hipStream_t stream)
{
    const float* x = (const float*)d_in[0];
    const float *W[5], *g[5], *bb[5], *m[5], *v[5];
    for (int li = 0; li < 5; li++) {
        W[li]  = (const float*)d_in[1 + li * 5 + 0];
        g[li]  = (const float*)d_in[1 + li * 5 + 1];
        bb[li] = (const float*)d_in[1 + li * 5 + 2];
        m[li]  = (const float*)d_in[1 + li * 5 + 3];
        v[li]  = (const float*)d_in[1 + li * 5 + 4];
    }
    const float* We = (const float*)d_in[26];
    const float* Wh = (const float*)d_in[27];
    const float* bh = (const float*)d_in[28];
    float* out = (float*)d_out;

    // workspace carve (float units). cat POINT-MAJOR [b][pt][512].
    float* ws   = (float*)d_ws;
    float* cat  = ws;                                   // 8,388,608
    float* qbuf = cat + (long)8388608;                  // 8,388,608 multi-purpose
    float* pbuf = qbuf + (long)8388608;                 // 4,194,304 (p-values)
    int*   idxb = (int*)(pbuf + 4194304);               // 327,680 ints
    float* xx   = (float*)(idxb + 327680);              // 16,384
    unsigned short* Wqh = (unsigned short*)(xx + 16384);// 32,768 shorts each
    unsigned short* Wql = Wqh + 32768;
    unsigned short* Wph = Wql + 32768;
    unsigned short* Wpl = Wph + 32768;
    unsigned short* W4h = Wpl + 32768;                  // 262,144 shorts
    unsigned short* W4l = W4h + 262144;
    float* shf  = (float*)(W4l + 262144);               // 512
    unsigned* ymax_u = (unsigned*)(shf + 512);          // 2,048 (encoded fp32)
    unsigned short* Ghi = (unsigned short*)qbuf;        // 2,097,152 shorts max
    unsigned short* Glo = Ghi + 2097152;
    float* knnd = qbuf + 2097152;                       // 1,310,720 floats
    int*   knni = (int*)(qbuf + 2097152 + 1310720);     // 1,310,720 ints
    float* qv   = qbuf + 2097152;                       // 4,194,304 floats (after knn)

    // ---- stage 0: knn on coords, straight from x ----
    prep0<<<dim3(16, NB), dim3(256), 0, stream>>>(x, xx, Ghi, Glo);
    fused_knn_mfma12<32><<<dim3(64 * NSL * NB), dim3(256), 0, stream>>>(
        Ghi, Glo, xx, knnd, knni);
    knn_merge4<<<dim3(64), dim3(256), 0, stream>>>(knnd, knni, idxb);
    edge0_fused<<<dim3(N_PTS / 4, NB), dim3(64, 4), 0, stream>>>(
        x, idxb, W[0], g[0], bb[0], m[0], v[0], cat, Ghi, Glo, xx);

    // ---- stages 1..3 ----
    const int Cs_[3]   = {64, 64, 128};
    const int co_[3]   = {64, 128, 256};
    const int outO_[3] = {64, 128, 256};
    for (int s = 0; s < 3; s++) {
        int C = Cs_[s], cout = co_[s];
        if (C == 64)
            fused_knn_mfma12<64><<<dim3(64 * NSL * NB), dim3(256), 0, stream>>>(
                Ghi, Glo, xx, knnd, knni);
        else
            fused_knn_mfma12<128><<<dim3(64 * NSL * NB), dim3(256), 0, stream>>>(
                Ghi, Glo, xx, knnd, knni);
        knn_merge4<<<dim3(64), dim3(256), 0, stream>>>(knnd, knni, idxb);

        int li = s + 1;
        fold_edge_bf16<<<dim3((C * cout + 255) / 256), dim3(256), 0, stream>>>(
            W[li], g[li], bb[li], m[li], v[li], Wqh, Wql, Wph, Wpl, shf, C, cout);
        if (C == 64)
            qp_mfma<64><<<dim3(64, cout / 64, NB), dim3(256), 0, stream>>>(
                Ghi, Glo, Wqh, Wql, Wph, Wpl, shf, qv, pbuf, cout);
        else
            qp_mfma<128><<<dim3(64, cout / 64, NB), dim3(256), 0, stream>>>(
                Ghi, Glo, Wqh, Wql, Wph, Wpl, shf, qv, pbuf, cout);
        if (s < 2)
            gather_max_fused<<<dim3(N_PTS * NB / 4), dim3(64, 4), 0, stream>>>(
                qv, pbuf, idxb, cat, cout, outO_[s], Ghi, Glo, xx);
        else
            gather_max_fused<<<dim3(N_PTS * NB / 4), dim3(64, 4), 0, stream>>>(
                qv, pbuf, idxb, cat, cout, outO_[s],
                (unsigned short*)nullptr, (unsigned short*)nullptr, (float*)nullptr);
    }

    // ---- stage 4: LDS-staged MFMA conv with fused global-max (atomic) ----
    fold_plain_bf16<<<dim3((512 * 512 + 255) / 256), dim3(256), 0, stream>>>(
        W[4], g[4], bb[4], m[4], v[4], W4h, W4l, shf, ymax_u, 512, 512);
    conv4h_mfma<<<dim3(2048), dim3(256), 0, stream>>>(
        cat, W4h, W4l, shf, ymax_u);

    // ---- head ----
    head_kernel<<<dim3(NB), dim3(128), 0, stream>>>(ymax_u, We, Wh, bh, out);
}

// Round 12
// 742.246 us; speedup vs baseline: 1.0992x; 1.0084x over previous
//
#include <hip/hip_runtime.h>
#include <cfloat>

#define N_PTS 4096
#define NB    4
#define KNN   20
#define EPSB  1e-5f
#define NSL   4          // knn candidate slices per batch-row (R22: NSL=8 regressed net)

typedef short s8v __attribute__((ext_vector_type(8)));
typedef float f4v __attribute__((ext_vector_type(4)));

// ---------------------------------------------------------------------------
// bf16 hi/lo split (round-to-nearest-even both halves)
// ---------------------------------------------------------------------------
__device__ __forceinline__ void bf16split(float x, unsigned short* h, unsigned short* l)
{
    unsigned u = __builtin_bit_cast(unsigned, x);
    unsigned hb = (u + 0x7fffu + ((u >> 16) & 1u)) >> 16;
    float hf = __builtin_bit_cast(float, hb << 16);
    float res = x - hf;
    unsigned u2 = __builtin_bit_cast(unsigned, res);
    unsigned lb = (u2 + 0x7fffu + ((u2 >> 16) & 1u)) >> 16;
    *h = (unsigned short)hb;
    *l = (unsigned short)lb;
}

// ---------------------------------------------------------------------------
// Packed key: fp32 distance (top 24 bits) | 8-bit lane-local ordinal.
// ---------------------------------------------------------------------------
__device__ __forceinline__ unsigned packkey(float d, int lc)
{
    d = fmaxf(d, 0.f);
    unsigned u = __builtin_bit_cast(unsigned, d);
    return (u & 0xFFFFFF00u) | (unsigned)lc;
}

// compare-exchange: a=min, b=max  (v_min_u32 + v_max_u32)
__device__ __forceinline__ void ce(unsigned& a, unsigned& b)
{
    unsigned lo = a < b ? a : b;
    b = a < b ? b : a;
    a = lo;
}

// ---------------------------------------------------------------------------
// R25 batch-8 top-20 maintenance (verified): Batcher sort-8 + half-clean +
// bitonic-8 tail + Batcher odd-even merge(12,8) + canonicalize.
// ---------------------------------------------------------------------------
__device__ __forceinline__ void insert8k(unsigned c0, unsigned c1, unsigned c2, unsigned c3,
                                         unsigned c4, unsigned c5, unsigned c6, unsigned c7,
                                         unsigned (&k)[KNN])
{
    ce(c0, c1); ce(c2, c3); ce(c0, c2); ce(c1, c3); ce(c1, c2);
    ce(c4, c5); ce(c6, c7); ce(c4, c6); ce(c5, c7); ce(c5, c6);
    ce(c0, c4); ce(c2, c6); ce(c2, c4);
    ce(c1, c5); ce(c3, c7); ce(c3, c5);
    ce(c1, c2); ce(c3, c4); ce(c5, c6);
    k[12] = k[12] < c7 ? k[12] : c7;
    k[13] = k[13] < c6 ? k[13] : c6;
    k[14] = k[14] < c5 ? k[14] : c5;
    k[15] = k[15] < c4 ? k[15] : c4;
    k[16] = k[16] < c3 ? k[16] : c3;
    k[17] = k[17] < c2 ? k[17] : c2;
    k[18] = k[18] < c1 ? k[18] : c1;
    k[19] = k[19] < c0 ? k[19] : c0;
    ce(k[12], k[16]); ce(k[13], k[17]); ce(k[14], k[18]); ce(k[15], k[19]);
    ce(k[12], k[14]); ce(k[13], k[15]); ce(k[16], k[18]); ce(k[17], k[19]);
    ce(k[12], k[13]); ce(k[14], k[15]); ce(k[16], k[17]); ce(k[18], k[19]);
    ce(k[0],  k[12]); ce(k[8],  k[12]); ce(k[4],  k[16]); ce(k[4],  k[8]);  ce(k[16], k[12]);
    ce(k[2],  k[14]); ce(k[10], k[14]); ce(k[6],  k[18]); ce(k[6],  k[10]); ce(k[18], k[14]);
    ce(k[2],  k[4]);  ce(k[6],  k[8]);  ce(k[10], k[16]); ce(k[18], k[12]);
    ce(k[1],  k[13]); ce(k[9],  k[13]); ce(k[5],  k[17]); ce(k[5],  k[9]);  ce(k[17], k[13]);
    ce(k[3],  k[15]); ce(k[11], k[15]); ce(k[7],  k[19]); ce(k[7],  k[11]); ce(k[19], k[15]);
    ce(k[3],  k[5]);  ce(k[7],  k[9]);  ce(k[11], k[17]); ce(k[19], k[13]);
    ce(k[1],  k[2]);  ce(k[3],  k[4]);  ce(k[5],  k[6]);  ce(k[7],  k[8]);  ce(k[9], k[10]);
    ce(k[11], k[16]); ce(k[17], k[18]); ce(k[19], k[12]); ce(k[13], k[14]);
    unsigned s;
    s = k[12]; k[12] = k[16]; k[16] = s;
    s = k[13]; k[13] = k[17]; k[17] = s;
    s = k[14]; k[14] = k[18]; k[18] = s;
    s = k[15]; k[15] = k[19]; k[19] = s;
}

// async global->LDS, 16B per lane; LDS dest = wave-uniform base + lane*16
__device__ __forceinline__ void gl2lds16(const void* g, void* l)
{
    __builtin_amdgcn_global_load_lds(
        (const __attribute__((address_space(1))) unsigned int*)g,
        (__attribute__((address_space(3))) unsigned int*)l,
        16, 0, 0);
}

// 16B-chunk swizzle (involution) — conv4h pattern (measured conflict-free).
__device__ __forceinline__ int swz(int g)
{
    return g ^ (((g >> 3) ^ (g >> 6)) & 7);
}

// R34: KDP-specific knn swizzle. Read pattern strides n by KDP/8 chunks
// (bank stride 0 mod 32); XOR the lane index n into the bank bits:
//   KDP=128: n = g>>4  ->  g ^ ((g>>4)&7)
//   KDP<=64: n-ish = g>>3 -> g ^ ((g>>3)&7)
// XOR touches only bits 0-2; selector uses bits >=3 -> involution for all g.
// Distinct bank slots across 8 consecutive n; residual 2-way is free (m136).
template<int KDP>
__device__ __forceinline__ int swzk(int g)
{
    if constexpr (KDP == 128) return g ^ ((g >> 4) & 7);
    else                      return g ^ ((g >> 3) & 7);
}

// monotone fp32 <-> u32 order-preserving encode (for atomicMax reduction)
__device__ __forceinline__ unsigned encf(float f)
{
    unsigned u = __builtin_bit_cast(unsigned, f);
    return (u & 0x80000000u) ? ~u : (u | 0x80000000u);
}
__device__ __forceinline__ float decf(unsigned u)
{
    return (u & 0x80000000u) ? __builtin_bit_cast(float, u ^ 0x80000000u)
                             : __builtin_bit_cast(float, ~u);
}

// ---------------------------------------------------------------------------
// R30: fused stage-0 prep (verified win).
// ---------------------------------------------------------------------------
__global__ __launch_bounds__(256)
void prep0(const float* __restrict__ x, float* __restrict__ xx,
           unsigned short* __restrict__ Ghi, unsigned short* __restrict__ Glo)
{
    int b = blockIdx.y;
    int i = blockIdx.x * 256 + threadIdx.x;
    const float* r = x + ((long)b * N_PTS + i) * 3;
    float v0 = r[0], v1 = r[1], v2 = r[2];
    float s = 0.f;
    s = fmaf(v0, v0, s);
    s = fmaf(v1, v1, s);
    s = fmaf(v2, v2, s);
    xx[(long)b * N_PTS + i] = s;

    float cv[3] = {v0, v1, v2};
    long o = ((long)b * N_PTS + i) * 32;
#pragma unroll
    for (int q = 0; q < 4; q++) {
        s8v hv, lv;
#pragma unroll
        for (int e = 0; e < 8; e++) {
            int k = q * 8 + e;
            float xv = (k < 3) ? cv[k] : 0.f;
            unsigned short h, l;
            bf16split(xv, &h, &l);
            hv[e] = (short)h;
            lv[e] = (short)l;
        }
        *(s8v*)&Ghi[o + q * 8] = hv;
        *(s8v*)&Glo[o + q * 8] = lv;
    }
}

// ---------------------------------------------------------------------------
// R31-best knn (R25 structure + XCD mapping + mk@21) + R34 swzk bank fix.
// ---------------------------------------------------------------------------
template<int KDP>
__global__ __launch_bounds__(256, 4)
void fused_knn_mfma12(const unsigned short* __restrict__ Ghi,
                      const unsigned short* __restrict__ Glo,
                      const float* __restrict__ xx,
                      float* __restrict__ knnd, int* __restrict__ knni)
{
    constexpr int KS = KDP / 32;
    constexpr int TS = 16 * KDP;
    constexpr int NCH2 = 4 * KDP;
    __shared__ union ShU {
        short cb[2][2][2 * TS];
        unsigned mk[4][16][4][21];
    } sh;

    int tid = threadIdx.x;
    int w = tid >> 6, L = tid & 63;
    int n = L & 15;
    int quad = L >> 4;

    int bid = blockIdx.x;
    int xcd = bid & 7;
    int slot = bid >> 3;
    int g = xcd + (slot >> 6) * 8;
    int qt = slot & 63;
    int slice = g & 3;
    int b = g >> 2;

    int q0 = qt * 64, qw = w * 16;
    const unsigned short* Gh = Ghi + (long)b * N_PTS * KDP;
    const unsigned short* Gl = Glo + (long)b * N_PTS * KDP;
    const float* xxb = xx + (long)b * N_PTS;

    s8v qhi[KS], qlo[KS];
    long qbase = (long)(q0 + qw + n) * KDP + quad * 8;
#pragma unroll
    for (int ks = 0; ks < KS; ks++) {
        qhi[ks] = *(const s8v*)&Gh[qbase + ks * 32];
        qlo[ks] = *(const s8v*)&Gl[qbase + ks * 32];
    }
    float xq = xxb[q0 + qw + n];

    unsigned k20[KNN];
#pragma unroll
    for (int j = 0; j < KNN; j++) k20[j] = 0xFFFFFFFFu;

    int poA[KS], poB[KS];
#pragma unroll
    for (int ks = 0; ks < KS; ks++) {
        int gL = n * (KDP / 8) + quad + ks * 4;
        poA[ks] = swzk<KDP>(gL) * 8;
        poB[ks] = swzk<KDP>(gL + 2 * KDP) * 8;
    }
    int gsrc = swzk<KDP>(tid);
    int w64 = tid & 192;

    {
        long tb = (long)(slice * 1024) * KDP;
        if (tid < NCH2) {
            gl2lds16((const char*)(Gh + tb) + gsrc * 16,
                     (char*)&sh.cb[0][0][0] + w64 * 16);
            gl2lds16((const char*)(Gl + tb) + gsrc * 16,
                     (char*)&sh.cb[0][1][0] + w64 * 16);
        }
        if constexpr (NCH2 == 512) {
            int gsrc2 = swzk<KDP>(tid + 256);
            gl2lds16((const char*)(Gh + tb) + gsrc2 * 16,
                     (char*)&sh.cb[0][0][0] + (256 + w64) * 16);
            gl2lds16((const char*)(Gl + tb) + gsrc2 * 16,
                     (char*)&sh.cb[0][1][0] + (256 + w64) * 16);
        }
    }
    __syncthreads();

    const float* xcp = xxb + slice * 1024 + quad * 4;

    for (int it = 0; it < 32; it++) {
        int cur = it & 1;
        if (it < 31) {
            long tb = (long)(slice * 1024 + (it + 1) * 32) * KDP;
            if (tid < NCH2) {
                gl2lds16((const char*)(Gh + tb) + gsrc * 16,
                         (char*)&sh.cb[cur ^ 1][0][0] + w64 * 16);
                gl2lds16((const char*)(Gl + tb) + gsrc * 16,
                         (char*)&sh.cb[cur ^ 1][1][0] + w64 * 16);
            }
            if constexpr (NCH2 == 512) {
                int gsrc2 = swzk<KDP>(tid + 256);
                gl2lds16((const char*)(Gh + tb) + gsrc2 * 16,
                         (char*)&sh.cb[cur ^ 1][0][0] + (256 + w64) * 16);
                gl2lds16((const char*)(Gl + tb) + gsrc2 * 16,
                         (char*)&sh.cb[cur ^ 1][1][0] + (256 + w64) * 16);
            }
        }

        const short* Ch = &sh.cb[cur][0][0];
        const short* Cl = &sh.cb[cur][1][0];
        f4v accA = {0.f, 0.f, 0.f, 0.f};
        f4v accB = {0.f, 0.f, 0.f, 0.f};
#pragma unroll
        for (int ks = 0; ks < KS; ks++) {
            s8v chiA = *(const s8v*)&Ch[poA[ks]];
            s8v cloA = *(const s8v*)&Cl[poA[ks]];
            accA = __builtin_amdgcn_mfma_f32_16x16x32_bf16(chiA, qhi[ks], accA, 0, 0, 0);
            accA = __builtin_amdgcn_mfma_f32_16x16x32_bf16(chiA, qlo[ks], accA, 0, 0, 0);
            accA = __builtin_amdgcn_mfma_f32_16x16x32_bf16(cloA, qhi[ks], accA, 0, 0, 0);
            s8v chiB = *(const s8v*)&Ch[poB[ks]];
            s8v cloB = *(const s8v*)&Cl[poB[ks]];
            accB = __builtin_amdgcn_mfma_f32_16x16x32_bf16(chiB, qhi[ks], accB, 0, 0, 0);
            accB = __builtin_amdgcn_mfma_f32_16x16x32_bf16(chiB, qlo[ks], accB, 0, 0, 0);
            accB = __builtin_amdgcn_mfma_f32_16x16x32_bf16(cloB, qhi[ks], accB, 0, 0, 0);
        }
        float4 xcA = *(const float4*)xcp;
        float4 xcB = *(const float4*)(xcp + 16);
        float xavA[4] = {xcA.x, xcA.y, xcA.z, xcA.w};
        float xavB[4] = {xcB.x, xcB.y, xcB.z, xcB.w};
        unsigned c[8];
#pragma unroll
        for (int r = 0; r < 4; r++) {
            float dA = xq + xavA[r] - 2.f * accA[r];
            float dB = xq + xavB[r] - 2.f * accB[r];
            c[r]     = packkey(dA, it * 8 + r);
            c[4 + r] = packkey(dB, it * 8 + 4 + r);
        }
        insert8k(c[0], c[1], c[2], c[3], c[4], c[5], c[6], c[7], k20);
        xcp += 32;
        __syncthreads();
    }

#pragma unroll
    for (int j = 0; j < KNN; j++) sh.mk[w][n][quad][j] = k20[j];
    __syncthreads();
    if (L < 16) {
        int p[4] = {0, 0, 0, 0};
        long o = (((long)b * NSL + slice) * N_PTS + (q0 + qw + L)) * KNN;
#pragma unroll
        for (int j = 0; j < KNN; j++) {
            unsigned bd = 0xFFFFFF00u; int bi = 0x7fffffff; int bq = 0;
#pragma unroll
            for (int qd = 0; qd < 4; qd++) {
                unsigned kk = sh.mk[w][L][qd][p[qd]];
                unsigned db = kk & 0xFFFFFF00u;
                int lc = (int)(kk & 0xFFu);
                int ci = slice * 1024 + (lc >> 2) * 16 + qd * 4 + (lc & 3);
                if (db < bd || (db == bd && ci < bi)) { bd = db; bi = ci; bq = qd; }
            }
            knnd[o + j] = __builtin_bit_cast(float, bd);
            knni[o + j] = bi;
            p[bq]++;
        }
    }
}

// ---------------------------------------------------------------------------
__global__ void knn_merge4(const float* __restrict__ knnd, const int* __restrict__ knni,
                           int* __restrict__ idxOut)
{
    int id = blockIdx.x * 256 + threadIdx.x;
    int b = id / N_PTS, i = id % N_PTS;
    const float* dl[NSL]; const int* il[NSL];
#pragma unroll
    for (int qt = 0; qt < NSL; qt++) {
        dl[qt] = knnd + (((long)b * NSL + qt) * N_PTS + i) * KNN;
        il[qt] = knni + (((long)b * NSL + qt) * N_PTS + i) * KNN;
    }
    int p[NSL];
#pragma unroll
    for (int qt = 0; qt < NSL; qt++) p[qt] = 0;
    int* o = idxOut + (long)id * KNN;
#pragma unroll
    for (int j = 0; j < KNN; j++) {
        float best = FLT_MAX; int bi = 0x7fffffff; int bq = 0;
#pragma unroll
        for (int qt = 0; qt < NSL; qt++) {
            float vv = (p[qt] < KNN) ? dl[qt][p[qt]] : FLT_MAX;
            int   ci = (p[qt] < KNN) ? il[qt][p[qt]] : 0x7fffffff;
            if (vv < best || (vv == best && ci < bi)) { best = vv; bi = ci; bq = qt; }
        }
        o[j] = bi;
        p[bq]++;
    }
}

// ---------------------------------------------------------------------------
// Fused q/p MFMA GEMM (edge stages) — unchanged.
// ---------------------------------------------------------------------------
template<int KDP>
__global__ __launch_bounds__(256)
void qp_mfma(const unsigned short* __restrict__ Ghi,
             const unsigned short* __restrict__ Glo,
             const unsigned short* __restrict__ Wqh, const unsigned short* __restrict__ Wql,
             const unsigned short* __restrict__ Wph, const unsigned short* __restrict__ Wpl,
             const float* __restrict__ shf,
             float* __restrict__ qv, float* __restrict__ pv, int cout)
{
    constexpr int KS = KDP / 32;
    int tid = threadIdx.x;
    int w = tid >> 6, L = tid & 63;
    int n = L & 15, quad = L >> 4;
    int b = blockIdx.z;
    int p0 = blockIdx.x * 64 + w * 16;

    s8v ah[KS], al[KS];
    long abase = ((long)b * N_PTS + p0 + n) * KDP + quad * 8;
#pragma unroll
    for (int ks = 0; ks < KS; ks++) {
        ah[ks] = *(const s8v*)&Ghi[abase + ks * 32];
        al[ks] = *(const s8v*)&Glo[abase + ks * 32];
    }

#pragma unroll
    for (int oc4 = 0; oc4 < 4; oc4++) {
        int oc = blockIdx.y * 4 + oc4;
        long wbase = (long)(oc * 16 + n) * KDP + quad * 8;
        f4v aq = {0.f, 0.f, 0.f, 0.f};
        f4v ap = {0.f, 0.f, 0.f, 0.f};
#pragma unroll
        for (int ks = 0; ks < KS; ks++) {
            s8v wh = *(const s8v*)&Wqh[wbase + ks * 32];
            s8v wl = *(const s8v*)&Wql[wbase + ks * 32];
            aq = __builtin_amdgcn_mfma_f32_16x16x32_bf16(ah[ks], wh, aq, 0, 0, 0);
            aq = __builtin_amdgcn_mfma_f32_16x16x32_bf16(ah[ks], wl, aq, 0, 0, 0);
            aq = __builtin_amdgcn_mfma_f32_16x16x32_bf16(al[ks], wh, aq, 0, 0, 0);
            s8v ph = *(const s8v*)&Wph[wbase + ks * 32];
            s8v pl = *(const s8v*)&Wpl[wbase + ks * 32];
            ap = __builtin_amdgcn_mfma_f32_16x16x32_bf16(ah[ks], ph, ap, 0, 0, 0);
            ap = __builtin_amdgcn_mfma_f32_16x16x32_bf16(ah[ks], pl, ap, 0, 0, 0);
            ap = __builtin_amdgcn_mfma_f32_16x16x32_bf16(al[ks], ph, ap, 0, 0, 0);
        }
        float sv = shf[oc * 16 + n];
#pragma unroll
        for (int r = 0; r < 4; r++) {
            long pt = p0 + quad * 4 + r;
            long o = ((long)b * N_PTS + pt) * cout + oc * 16 + n;
            qv[o] = aq[r];
            pv[o] = ap[r] + sv;
        }
    }
}

// ---------------------------------------------------------------------------
// Stage-4 conv with fused global-max (R30) + R33 XCD grouping (verified).
// ---------------------------------------------------------------------------
__global__ __launch_bounds__(256)
void conv4h_mfma(const float* __restrict__ cat,
                 const unsigned short* __restrict__ W4h, const unsigned short* __restrict__ W4l,
                 const float* __restrict__ shf, unsigned* __restrict__ ymax_u)
{
    __shared__ short Wbs[2][2][2048];
    __shared__ float Cbs[2][2048];

    int tid = threadIdx.x;
    int w = tid >> 6, L = tid & 63;
    int n = L & 15, quad = L >> 4;

    int bid = blockIdx.x;
    int xcd = bid & 7;
    int s = bid >> 3;
    int gidx = s >> 3;
    int ob = s & 7;
    int gg = xcd + gidx * 8;
    int b = gg >> 6;
    int p0b = (gg & 63) * 64;
    int ob0 = ob * 64;
    int w64 = tid & 192;

    const char* catb = (const char*)(cat + ((long)b * N_PTS + p0b) * 512);
    const char* whb  = (const char*)(W4h + (long)ob0 * 512);
    const char* wlb  = (const char*)(W4l + (long)ob0 * 512);

    int gw = swz(tid);
    int gc0 = swz(tid);
    int gc1 = swz(tid + 256);

    long woff = (long)(gw >> 2) * 1024 + (gw & 3) * 16;
    long coff0 = (long)(gc0 >> 3) * 2048 + (gc0 & 7) * 16;
    long coff1 = (long)(gc1 >> 3) * 2048 + (gc1 & 7) * 16;

    {
        gl2lds16(whb + woff, (char*)&Wbs[0][0][0] + w64 * 16);
        gl2lds16(wlb + woff, (char*)&Wbs[0][1][0] + w64 * 16);
        gl2lds16(catb + coff0, (char*)&Cbs[0][0] + w64 * 16);
        gl2lds16(catb + coff1, (char*)&Cbs[0][0] + (256 + w64) * 16);
    }
    __syncthreads();

    int p8 = (w * 16 + n) * 8;
    int cch0 = swz(p8 + quad * 2) * 16;
    int cch1 = swz(p8 + quad * 2 + 1) * 16;
    int wch[4];
#pragma unroll
    for (int c4 = 0; c4 < 4; c4++) wch[c4] = swz((c4 * 16 + n) * 4 + quad) * 16;

    f4v acc[4];
#pragma unroll
    for (int c4 = 0; c4 < 4; c4++) acc[c4] = {0.f, 0.f, 0.f, 0.f};

    for (int ks = 0; ks < 16; ks++) {
        int cur = ks & 1;
        if (ks < 15) {
            long t2 = (long)(ks + 1) * 64;
            long tc = (long)(ks + 1) * 128;
            gl2lds16(whb + t2 + woff, (char*)&Wbs[cur ^ 1][0][0] + w64 * 16);
            gl2lds16(wlb + t2 + woff, (char*)&Wbs[cur ^ 1][1][0] + w64 * 16);
            gl2lds16(catb + tc + coff0, (char*)&Cbs[cur ^ 1][0] + w64 * 16);
            gl2lds16(catb + tc + coff1, (char*)&Cbs[cur ^ 1][0] + (256 + w64) * 16);
        }

        float4 c0 = *(const float4*)((const char*)&Cbs[cur][0] + cch0);
        float4 c1 = *(const float4*)((const char*)&Cbs[cur][0] + cch1);
        float fv[8] = {c0.x, c0.y, c0.z, c0.w, c1.x, c1.y, c1.z, c1.w};
        s8v ah, al;
#pragma unroll
        for (int i = 0; i < 8; i++) {
            unsigned short h, l;
            bf16split(fv[i], &h, &l);
            ah[i] = (short)h;
            al[i] = (short)l;
        }
#pragma unroll
        for (int c4 = 0; c4 < 4; c4++) {
            s8v wh = *(const s8v*)((const char*)&Wbs[cur][0][0] + wch[c4]);
            s8v wl = *(const s8v*)((const char*)&Wbs[cur][1][0] + wch[c4]);
            acc[c4] = __builtin_amdgcn_mfma_f32_16x16x32_bf16(ah, wh, acc[c4], 0, 0, 0);
            acc[c4] = __builtin_amdgcn_mfma_f32_16x16x32_bf16(ah, wl, acc[c4], 0, 0, 0);
            acc[c4] = __builtin_amdgcn_mfma_f32_16x16x32_bf16(al, wh, acc[c4], 0, 0, 0);
        }
        __syncthreads();
    }

#pragma unroll
    for (int c4 = 0; c4 < 4; c4++) {
        int o = ob0 + c4 * 16 + n;
        float sv = shf[o];
        float mx = -FLT_MAX;
#pragma unroll
        for (int r = 0; r < 4; r++) {
            float y = acc[c4][r] + sv;
            y = y >= 0.f ? y : 0.2f * y;
            mx = fmaxf(mx, y);
        }
        mx = fmaxf(mx, __shfl_xor(mx, 16));
        mx = fmaxf(mx, __shfl_xor(mx, 32));
        if (quad == 0)
            atomicMax(&ymax_u[(long)b * 512 + o], encf(mx));
    }
}

// ---------------------------------------------------------------------------
// Weight folding to bf16 hi/lo, [o][c] layout.
// ---------------------------------------------------------------------------
__global__ void fold_edge_bf16(const float* __restrict__ W, const float* __restrict__ g,
                               const float* __restrict__ bb, const float* __restrict__ m,
                               const float* __restrict__ v,
                               unsigned short* __restrict__ Wqh, unsigned short* __restrict__ Wql,
                               unsigned short* __restrict__ Wph, unsigned short* __restrict__ Wpl,
                               float* __restrict__ shift, int C, int cout)
{
    int id = blockIdx.x * 256 + threadIdx.x;
    if (id < C * cout) {
        int o = id / C;
        int c = id % C;
        float sc = g[o] * rsqrtf(v[o] + EPSB);
        float wd = W[(long)o * 2 * C + c];
        float wc = W[(long)o * 2 * C + C + c];
        bf16split(sc * wd, &Wqh[id], &Wql[id]);
        bf16split(sc * (wc - wd), &Wph[id], &Wpl[id]);
    }
    if (id < cout) {
        float sc = g[id] * rsqrtf(v[id] + EPSB);
        shift[id] = bb[id] - m[id] * sc;
    }
}

// R30: also zero-inits ymax_u (runs right before conv4h each launch).
__global__ void fold_plain_bf16(const float* __restrict__ W, const float* __restrict__ g,
                                const float* __restrict__ bb, const float* __restrict__ m,
                                const float* __restrict__ v,
                                unsigned short* __restrict__ W4h, unsigned short* __restrict__ W4l,
                                float* __restrict__ shift, unsigned* __restrict__ ymax_u,
                                int C, int cout)
{
    int id = blockIdx.x * 256 + threadIdx.x;
    if (id < C * cout) {
        int o = id / C;
        int c = id % C;
        float sc = g[o] * rsqrtf(v[o] + EPSB);
        bf16split(sc * W[(long)o * C + c], &W4h[id], &W4l[id]);
    }
    if (id < cout) {
        float sc = g[id] * rsqrtf(v[id] + EPSB);
        shift[id] = bb[id] - m[id] * sc;
    }
    if (id < 2048) ymax_u[id] = 0u;   // encf lower bound
}

// ---------------------------------------------------------------------------
// Gather+max with R33 XCD decode (verified win).
// ---------------------------------------------------------------------------
__global__ void gather_max_fused(const float* __restrict__ q, const float* __restrict__ p,
                                 const int* __restrict__ idx, float* __restrict__ cat,
                                 int cout, int c_off,
                                 unsigned short* __restrict__ Ghi,
                                 unsigned short* __restrict__ Glo,
                                 float* __restrict__ xx)
{
    int bid = blockIdx.x;
    int xcd = bid & 7;
    int b = xcd & 3;
    int half = xcd >> 2;
    int slot = bid >> 3;                 // 0..511
    int i = (half * 512 + slot) * 4 + threadIdx.y;
    int tx = threadIdx.x;
    const int* ip = idx + ((long)b * N_PTS + i) * KNN;
    int js[KNN];
#pragma unroll
    for (int k = 0; k < KNN; k++) js[k] = ip[k];
    const float* qb = q + (long)b * N_PTS * cout;
    const float* pb = p + ((long)b * N_PTS + i) * cout;
    float* ob = cat + ((long)b * N_PTS + i) * 512 + c_off;
    float ssum = 0.f;
    for (int o0 = 0; o0 < cout; o0 += 64) {
        int o = o0 + tx;
        float pv = pb[o];
        float mx = -FLT_MAX;
#pragma unroll
        for (int k = 0; k < KNN; k++) {
            float val = qb[(long)js[k] * cout + o] + pv;
            val = val >= 0.f ? val : 0.2f * val;
            mx = fmaxf(mx, val);
        }
        ob[o] = mx;
        if (Ghi) {
            unsigned short h, l;
            bf16split(mx, &h, &l);
            long go = ((long)b * N_PTS + i) * cout + o;
            Ghi[go] = h;
            Glo[go] = l;
            ssum = fmaf(mx, mx, ssum);
        }
    }
    if (Ghi) {
#pragma unroll
        for (int off = 32; off > 0; off >>= 1) ssum += __shfl_xor(ssum, off);
        if (tx == 0) xx[(long)b * N_PTS + i] = ssum;
    }
}

// ---------------------------------------------------------------------------
// Block-0 edge conv (R29 form — parallel merge done by knn_merge4 upstream).
// ---------------------------------------------------------------------------
__global__ void edge0_fused(const float* __restrict__ x, const int* __restrict__ idx,
                            const float* __restrict__ W0, const float* __restrict__ g0,
                            const float* __restrict__ b0, const float* __restrict__ m0,
                            const float* __restrict__ v0, float* __restrict__ cat,
                            unsigned short* __restrict__ Ghi,
                            unsigned short* __restrict__ Glo,
                            float* __restrict__ xx)
{
    int b = blockIdx.y;
    int i = blockIdx.x * 4 + threadIdx.y;
    int o = threadIdx.x;
    const float* xc = x + ((long)b * N_PTS + i) * 3;
    float cx = xc[0], cy = xc[1], cz = xc[2];
    float w[9];
#pragma unroll
    for (int c = 0; c < 9; c++) w[c] = W0[o * 9 + c];
    float sc = g0[o] * rsqrtf(v0[o] + EPSB);
    float sh = b0[o] - m0[o] * sc;
    const int* ip = idx + ((long)b * N_PTS + i) * KNN;
    float mx = -FLT_MAX;
#pragma unroll
    for (int k = 0; k < KNN; k++) {
        const float* xn = x + ((long)b * N_PTS + ip[k]) * 3;
        float nx = xn[0], ny = xn[1], nz = xn[2];
        float dx = nx - cx, dy = ny - cy, dz = nz - cz;
        float crx = cy * nz - cz * ny;
        float cry = cz * nx - cx * nz;
        float crz = cx * ny - cy * nx;
        float y = w[0] * dx + w[1] * dy + w[2] * dz
                + w[3] * crx + w[4] * cry + w[5] * crz
                + w[6] * cx + w[7] * cy + w[8] * cz;
        y = y * sc + sh;
        y = y >= 0.f ? y : 0.2f * y;
        mx = fmaxf(mx, y);
    }
    cat[((long)b * N_PTS + i) * 512 + o] = mx;
    unsigned short h, l;
    bf16split(mx, &h, &l);
    long go = ((long)b * N_PTS + i) * 64 + o;
    Ghi[go] = h;
    Glo[go] = l;
    float ssum = mx * mx;
#pragma unroll
    for (int off = 32; off > 0; off >>= 1) ssum += __shfl_xor(ssum, off);
    if (o == 0) xx[(long)b * N_PTS + i] = ssum;
}

// R30: decodes the atomicMax-encoded ymax.
__global__ void head_kernel(const unsigned* __restrict__ ymax_u, const float* __restrict__ We,
                            const float* __restrict__ Wh, const float* __restrict__ bh,
                            float* __restrict__ out)
{
    __shared__ float emb[128];
    __shared__ float yv[512];
    int b = blockIdx.x, t = threadIdx.x;
    for (int s = t; s < 512; s += 128) yv[s] = decf(ymax_u[(long)b * 512 + s]);
    __syncthreads();
    float acc = 0.f;
    for (int c = 0; c < 512; c++) acc = fmaf(yv[c], We[(long)t * 512 + c], acc);
    emb[t] = acc;
    __syncthreads();
    float acc2 = bh[t];
    for (int ff = 0; ff < 128; ff++) acc2 = fmaf(emb[ff], Wh[(long)t * 128 + ff], acc2);
    out[(long)b * 128 + t] = acc2;
}

// ---------------------------------------------------------------------------
extern "C" void kernel_launch(void* const* d_in, const int* in_sizes, int n_in,
                              void* d_out, int out_size, void* d_ws, size_t ws_size,
                              hipStream_t stream)
{
    const float* x = (const float*)d_in[0];
    const float *W[5], *g[5], *bb[5], *m[5], *v[5];
    for (int li = 0; li < 5; li++) {
        W[li]  = (const float*)d_in[1 + li * 5 + 0];
        g[li]  = (const float*)d_in[1 + li * 5 + 1];
        bb[li] = (const float*)d_in[1 + li * 5 + 2];
        m[li]  = (const float*)d_in[1 + li * 5 + 3];
        v[li]  = (const float*)d_in[1 + li * 5 + 4];
    }
    const float* We = (const float*)d_in[26];
    const float* Wh = (const float*)d_in[27];
    const float* bh = (const float*)d_in[28];
    float* out = (float*)d_out;

    // workspace carve (float units). cat POINT-MAJOR [b][pt][512].
    float* ws   = (float*)d_ws;
    float* cat  = ws;                                   // 8,388,608
    float* qbuf = cat + (long)8388608;                  // 8,388,608 multi-purpose
    float* pbuf = qbuf + (long)8388608;                 // 4,194,304 (p-values)
    int*   idxb = (int*)(pbuf + 4194304);               // 327,680 ints
    float* xx   = (float*)(idxb + 327680);              // 16,384
    unsigned short* Wqh = (unsigned short*)(xx + 16384);// 32,768 shorts each
    unsigned short* Wql = Wqh + 32768;
    unsigned short* Wph = Wql + 32768;
    unsigned short* Wpl = Wph + 32768;
    unsigned short* W4h = Wpl + 32768;                  // 262,144 shorts
    unsigned short* W4l = W4h + 262144;
    float* shf  = (float*)(W4l + 262144);               // 512
    unsigned* ymax_u = (unsigned*)(shf + 512);          // 2,048 (encoded fp32)
    unsigned short* Ghi = (unsigned short*)qbuf;        // 2,097,152 shorts max
    unsigned short* Glo = Ghi + 2097152;
    float* knnd = qbuf + 2097152;                       // 1,310,720 floats
    int*   knni = (int*)(qbuf + 2097152 + 1310720);     // 1,310,720 ints
    float* qv   = qbuf + 2097152;                       // 4,194,304 floats (after knn)

    // ---- stage 0: knn on coords, straight from x ----
    prep0<<<dim3(16, NB), dim3(256), 0, stream>>>(x, xx, Ghi, Glo);
    fused_knn_mfma12<32><<<dim3(64 * NSL * NB), dim3(256), 0, stream>>>(
        Ghi, Glo, xx, knnd, knni);
    knn_merge4<<<dim3(64), dim3(256), 0, stream>>>(knnd, knni, idxb);
    edge0_fused<<<dim3(N_PTS / 4, NB), dim3(64, 4), 0, stream>>>(
        x, idxb, W[0], g[0], bb[0], m[0], v[0], cat, Ghi, Glo, xx);

    // ---- stages 1..3 ----
    const int Cs_[3]   = {64, 64, 128};
    const int co_[3]   = {64, 128, 256};
    const int outO_[3] = {64, 128, 256};
    for (int s = 0; s < 3; s++) {
        int C = Cs_[s], cout = co_[s];
        if (C == 64)
            fused_knn_mfma12<64><<<dim3(64 * NSL * NB), dim3(256), 0, stream>>>(
                Ghi, Glo, xx, knnd, knni);
        else
            fused_knn_mfma12<128><<<dim3(64 * NSL * NB), dim3(256), 0, stream>>>(
                Ghi, Glo, xx, knnd, knni);
        knn_merge4<<<dim3(64), dim3(256), 0, stream>>>(knnd, knni, idxb);

        int li = s + 1;
        fold_edge_bf16<<<dim3((C * cout + 255) / 256), dim3(256), 0, stream>>>(
            W[li], g[li], bb[li], m[li], v[li], Wqh, Wql, Wph, Wpl, shf, C, cout);
        if (C == 64)
            qp_mfma<64><<<dim3(64, cout / 64, NB), dim3(256), 0, stream>>>(
                Ghi, Glo, Wqh, Wql, Wph, Wpl, shf, qv, pbuf, cout);
        else
            qp_mfma<128><<<dim3(64, cout / 64, NB), dim3(256), 0, stream>>>(
                Ghi, Glo, Wqh, Wql, Wph, Wpl, shf, qv, pbuf, cout);
        if (s < 2)
            gather_max_fused<<<dim3(N_PTS * NB / 4), dim3(64, 4), 0, stream>>>(
                qv, pbuf, idxb, cat, cout, outO_[s], Ghi, Glo, xx);
        else
            gather_max_fused<<<dim3(N_PTS * NB / 4), dim3(64, 4), 0, stream>>>(
                qv, pbuf, idxb, cat, cout, outO_[s],
                (unsigned short*)nullptr, (unsigned short*)nullptr, (float*)nullptr);
    }

    // ---- stage 4: LDS-staged MFMA conv with fused global-max (atomic) ----
    fold_plain_bf16<<<dim3((512 * 512 + 255) / 256), dim3(256), 0, stream>>>(
        W[4], g[4], bb[4], m[4], v[4], W4h, W4l, shf, ymax_u, 512, 512);
    conv4h_mfma<<<dim3(2048), dim3(256), 0, stream>>>(
        cat, W4h, W4l, shf, ymax_u);

    // ---- head ----
    head_kernel<<<dim3(NB), dim3(128), 0, stream>>>(ymax_u, We, Wh, bh, out);
}